// Round 1
// baseline (639.043 us; speedup 1.0000x reference)
//
#include <hip/hip_runtime.h>
#include <math.h>

#define N_NODES 50000
#define F_IN    128
#define HIDC    64
#define HEADS   4
#define C1      (HEADS*HIDC)   // 256
#define F_OUT   128
#define NE      800000
#define NET     (NE + N_NODES) // 850000 edges incl self-loops
#define NEG_SLOPE 0.2f

// ---------------- CSR build ----------------

__global__ void count_deg(const int* __restrict__ ei, int* __restrict__ deg) {
  int e = blockIdx.x * blockDim.x + threadIdx.x;
  if (e >= NET) return;
  int d = (e < NE) ? ei[NE + e] : (e - NE);
  atomicAdd(&deg[d], 1);
}

__global__ __launch_bounds__(1024) void scan_rowptr(const int* __restrict__ deg,
                                                    int* __restrict__ rowptr) {
  __shared__ int sums[1024];
  int t = threadIdx.x;
  const int PER = (N_NODES + 1023) / 1024;  // 49
  int base = t * PER;
  int s = 0;
  for (int i = 0; i < PER; ++i) {
    int idx = base + i;
    if (idx < N_NODES) s += deg[idx];
  }
  sums[t] = s;
  __syncthreads();
  for (int off = 1; off < 1024; off <<= 1) {
    int v = (t >= off) ? sums[t - off] : 0;
    __syncthreads();
    sums[t] += v;
    __syncthreads();
  }
  int run = (t == 0) ? 0 : sums[t - 1];
  for (int i = 0; i < PER; ++i) {
    int idx = base + i;
    if (idx < N_NODES) {
      run += deg[idx];
      rowptr[idx + 1] = run;
    }
  }
  if (t == 0) rowptr[0] = 0;
}

__global__ void scatter_edges(const int* __restrict__ ei, const int* __restrict__ rowptr,
                              int* __restrict__ fill, int* __restrict__ colsrc) {
  int e = blockIdx.x * blockDim.x + threadIdx.x;
  if (e >= NET) return;
  int s, d;
  if (e < NE) { s = ei[e]; d = ei[NE + e]; }
  else        { s = e - NE; d = s; }
  int pos = atomicAdd(&fill[d], 1);
  colsrc[rowptr[d] + pos] = s;
}

// ---------------- fp32 tiled GEMM: C[M,NCOL] = A[M,K] @ B[K,NCOL] ----------------
// 64x64 block tile, 4x4 micro-tile, 256 threads. Rows guarded by N_NODES.

template<int K, int NCOL>
__global__ __launch_bounds__(256) void gemm_tile(const float* __restrict__ A,
                                                 const float* __restrict__ B,
                                                 float* __restrict__ C) {
  __shared__ float As[32][68];   // [k][m], pad 68 -> 16B-aligned rows, conflict-free reads
  __shared__ float Bs[32][64];   // [k][n]
  const int tid = threadIdx.x;
  const int tx = tid & 15;       // col group (4 cols each)
  const int ty = tid >> 4;       // row group (4 rows each)
  const int row0 = blockIdx.y * 64;
  const int col0 = blockIdx.x * 64;
  float acc[4][4] = {};

  for (int k0 = 0; k0 < K; k0 += 32) {
#pragma unroll
    for (int i = 0; i < 8; ++i) {          // A tile 64x32 -> As[k][m]
      int idx = tid + i * 256;
      int m = idx >> 5, k = idx & 31;
      int row = row0 + m;
      As[k][m] = (row < N_NODES) ? A[(size_t)row * K + k0 + k] : 0.f;
    }
#pragma unroll
    for (int i = 0; i < 8; ++i) {          // B tile 32x64
      int idx = tid + i * 256;
      int kb = idx >> 6, c = idx & 63;
      Bs[kb][c] = B[(size_t)(k0 + kb) * NCOL + col0 + c];
    }
    __syncthreads();
#pragma unroll
    for (int kk = 0; kk < 32; ++kk) {
      float4 av = *(const float4*)&As[kk][ty * 4];
      float4 bv = *(const float4*)&Bs[kk][tx * 4];
      acc[0][0] = fmaf(av.x, bv.x, acc[0][0]);
      acc[0][1] = fmaf(av.x, bv.y, acc[0][1]);
      acc[0][2] = fmaf(av.x, bv.z, acc[0][2]);
      acc[0][3] = fmaf(av.x, bv.w, acc[0][3]);
      acc[1][0] = fmaf(av.y, bv.x, acc[1][0]);
      acc[1][1] = fmaf(av.y, bv.y, acc[1][1]);
      acc[1][2] = fmaf(av.y, bv.z, acc[1][2]);
      acc[1][3] = fmaf(av.y, bv.w, acc[1][3]);
      acc[2][0] = fmaf(av.z, bv.x, acc[2][0]);
      acc[2][1] = fmaf(av.z, bv.y, acc[2][1]);
      acc[2][2] = fmaf(av.z, bv.z, acc[2][2]);
      acc[2][3] = fmaf(av.z, bv.w, acc[2][3]);
      acc[3][0] = fmaf(av.w, bv.x, acc[3][0]);
      acc[3][1] = fmaf(av.w, bv.y, acc[3][1]);
      acc[3][2] = fmaf(av.w, bv.z, acc[3][2]);
      acc[3][3] = fmaf(av.w, bv.w, acc[3][3]);
    }
    __syncthreads();
  }
#pragma unroll
  for (int i = 0; i < 4; ++i) {
    int row = row0 + ty * 4 + i;
    if (row < N_NODES) {
      float4 v = make_float4(acc[i][0], acc[i][1], acc[i][2], acc[i][3]);
      *(float4*)&C[(size_t)row * NCOL + col0 + tx * 4] = v;
    }
  }
}

// ---------------- attention logits ----------------

// layer1: per node, 4 heads x 64 ch. block=256, one node per block.
__global__ __launch_bounds__(256) void al_heads(const float* __restrict__ H,
                                                const float* __restrict__ a_s,
                                                const float* __restrict__ a_d,
                                                float* __restrict__ als,
                                                float* __restrict__ ald) {
  int n = blockIdx.x;
  int tid = threadIdx.x;
  int h = tid >> 6, lane = tid & 63;
  float v = H[(size_t)n * C1 + tid];
  float ps = v * a_s[tid], pd = v * a_d[tid];
#pragma unroll
  for (int off = 32; off; off >>= 1) {
    ps += __shfl_down(ps, off, 64);
    pd += __shfl_down(pd, off, 64);
  }
  if (lane == 0) { als[n * HEADS + h] = ps; ald[n * HEADS + h] = pd; }
}

// layer2: 1 head x 128 ch. wave per node, lane covers c and c+64.
__global__ __launch_bounds__(256) void al_single(const float* __restrict__ H2,
                                                 const float* __restrict__ a_s,
                                                 const float* __restrict__ a_d,
                                                 float* __restrict__ als,
                                                 float* __restrict__ ald) {
  int wave = threadIdx.x >> 6, lane = threadIdx.x & 63;
  int n = blockIdx.x * 4 + wave;
  if (n >= N_NODES) return;
  float v0 = H2[(size_t)n * F_OUT + lane];
  float v1 = H2[(size_t)n * F_OUT + 64 + lane];
  float ps = v0 * a_s[lane] + v1 * a_s[64 + lane];
  float pd = v0 * a_d[lane] + v1 * a_d[64 + lane];
#pragma unroll
  for (int off = 32; off; off >>= 1) {
    ps += __shfl_down(ps, off, 64);
    pd += __shfl_down(pd, off, 64);
  }
  if (lane == 0) { als[n] = ps; ald[n] = pd; }
}

// ---------------- fused segment-softmax + aggregation ----------------

// layer1: block = node, wave = head, lane = channel. Online softmax over incoming edges.
// Writes relu(out + b1) -> X2.
__global__ __launch_bounds__(256) void attn1(const int* __restrict__ rowptr,
                                             const int* __restrict__ colsrc,
                                             const float* __restrict__ H,
                                             const float* __restrict__ als,
                                             const float* __restrict__ ald,
                                             const float* __restrict__ b1,
                                             float* __restrict__ X2) {
  int n = blockIdx.x;
  int h = threadIdx.x >> 6;
  int lane = threadIdx.x & 63;
  float a_d = ald[n * HEADS + h];
  int beg = rowptr[n], end = rowptr[n + 1];
  float m = -1e30f, s = 0.f, acc = 0.f;
  for (int i = beg; i < end; ++i) {
    int src = colsrc[i];
    float sc = als[src * HEADS + h] + a_d;
    sc = sc > 0.f ? sc : NEG_SLOPE * sc;
    float nm = fmaxf(m, sc);
    float scale = __expf(m - nm);
    float p = __expf(sc - nm);
    s = s * scale + p;
    acc = acc * scale + p * H[(size_t)src * C1 + h * HIDC + lane];
    m = nm;
  }
  float o = acc / s + b1[h * HIDC + lane];
  X2[(size_t)n * C1 + h * HIDC + lane] = fmaxf(o, 0.f);
}

// layer2: wave per node (4 nodes/block), lane covers channels c and c+64. Writes d_out.
__global__ __launch_bounds__(256) void attn2(const int* __restrict__ rowptr,
                                             const int* __restrict__ colsrc,
                                             const float* __restrict__ H2,
                                             const float* __restrict__ als,
                                             const float* __restrict__ ald,
                                             const float* __restrict__ b2,
                                             float* __restrict__ out) {
  int wave = threadIdx.x >> 6, lane = threadIdx.x & 63;
  int n = blockIdx.x * 4 + wave;
  if (n >= N_NODES) return;
  float a_d = ald[n];
  int beg = rowptr[n], end = rowptr[n + 1];
  float m = -1e30f, s = 0.f, a0 = 0.f, a1 = 0.f;
  for (int i = beg; i < end; ++i) {
    int src = colsrc[i];
    float sc = als[src] + a_d;
    sc = sc > 0.f ? sc : NEG_SLOPE * sc;
    float nm = fmaxf(m, sc);
    float scale = __expf(m - nm);
    float p = __expf(sc - nm);
    s = s * scale + p;
    a0 = a0 * scale + p * H2[(size_t)src * F_OUT + lane];
    a1 = a1 * scale + p * H2[(size_t)src * F_OUT + 64 + lane];
    m = nm;
  }
  out[(size_t)n * F_OUT + lane] = a0 / s + b2[lane];
  out[(size_t)n * F_OUT + 64 + lane] = a1 / s + b2[64 + lane];
}

// ---------------- launch ----------------

extern "C" void kernel_launch(void* const* d_in, const int* in_sizes, int n_in,
                              void* d_out, int out_size, void* d_ws, size_t ws_size,
                              hipStream_t stream) {
  const float* X   = (const float*)d_in[0];
  const int*   EI  = (const int*)d_in[1];   // [2, NE]: row0=src, row1=dst
  const float* W1  = (const float*)d_in[2];
  const float* a1s = (const float*)d_in[3];
  const float* a1d = (const float*)d_in[4];
  const float* b1  = (const float*)d_in[5];
  const float* W2  = (const float*)d_in[6];
  const float* a2s = (const float*)d_in[7];
  const float* a2d = (const float*)d_in[8];
  const float* b2  = (const float*)d_in[9];
  float* out = (float*)d_out;

  char* ws = (char*)d_ws;
  size_t off = 0;
  auto alloc = [&](size_t bytes) -> void* {
    void* p = ws + off;
    off += (bytes + 255) & ~(size_t)255;
    return p;
  };
  int* deg     = (int*)alloc((size_t)N_NODES * 4);
  int* fill    = (int*)alloc((size_t)N_NODES * 4);
  int* rowptr  = (int*)alloc((size_t)(N_NODES + 1) * 4);
  int* colsrc  = (int*)alloc((size_t)NET * 4);
  float* H1    = (float*)alloc((size_t)N_NODES * C1 * 4);
  float* ALS1  = (float*)alloc((size_t)N_NODES * HEADS * 4);
  float* ALD1  = (float*)alloc((size_t)N_NODES * HEADS * 4);
  float* X2    = (float*)alloc((size_t)N_NODES * C1 * 4);
  float* H2    = (float*)alloc((size_t)N_NODES * F_OUT * 4);
  float* ALS2  = (float*)alloc((size_t)N_NODES * 4);
  float* ALD2  = (float*)alloc((size_t)N_NODES * 4);

  hipMemsetAsync(deg, 0, (size_t)N_NODES * 4, stream);
  hipMemsetAsync(fill, 0, (size_t)N_NODES * 4, stream);

  // CSR build (shared by both layers)
  count_deg<<<(NET + 255) / 256, 256, 0, stream>>>(EI, deg);
  scan_rowptr<<<1, 1024, 0, stream>>>(deg, rowptr);
  scatter_edges<<<(NET + 255) / 256, 256, 0, stream>>>(EI, rowptr, fill, colsrc);

  // layer 1
  {
    dim3 grid(C1 / 64, (N_NODES + 63) / 64);
    gemm_tile<F_IN, C1><<<grid, 256, 0, stream>>>(X, W1, H1);
  }
  al_heads<<<N_NODES, 256, 0, stream>>>(H1, a1s, a1d, ALS1, ALD1);
  attn1<<<N_NODES, 256, 0, stream>>>(rowptr, colsrc, H1, ALS1, ALD1, b1, X2);

  // layer 2
  {
    dim3 grid(F_OUT / 64, (N_NODES + 63) / 64);
    gemm_tile<C1, F_OUT><<<grid, 256, 0, stream>>>(X2, W2, H2);
  }
  al_single<<<(N_NODES + 3) / 4, 256, 0, stream>>>(H2, a2s, a2d, ALS2, ALD2);
  attn2<<<(N_NODES + 3) / 4, 256, 0, stream>>>(rowptr, colsrc, H2, ALS2, ALD2, b2, out);
}

// Round 2
// 570.988 us; speedup vs baseline: 1.1192x; 1.1192x over previous
//
#include <hip/hip_runtime.h>
#include <math.h>

#define N_NODES 50000
#define F_IN    128
#define HIDC    64
#define HEADS   4
#define C1      (HEADS*HIDC)   // 256
#define F_OUT   128
#define NE      800000
#define NET     (NE + N_NODES) // 850000 edges incl self-loops
#define NEG_SLOPE 0.2f

// ---------------- CSR build ----------------

__global__ void count_deg(const int* __restrict__ ei, int* __restrict__ deg) {
  int e = blockIdx.x * blockDim.x + threadIdx.x;
  if (e >= NET) return;
  int d = (e < NE) ? ei[NE + e] : (e - NE);
  atomicAdd(&deg[d], 1);
}

__global__ __launch_bounds__(1024) void scan_rowptr(const int* __restrict__ deg,
                                                    int* __restrict__ rowptr) {
  __shared__ int sums[1024];
  int t = threadIdx.x;
  const int PER = (N_NODES + 1023) / 1024;  // 49
  int base = t * PER;
  int s = 0;
  for (int i = 0; i < PER; ++i) {
    int idx = base + i;
    if (idx < N_NODES) s += deg[idx];
  }
  sums[t] = s;
  __syncthreads();
  for (int off = 1; off < 1024; off <<= 1) {
    int v = (t >= off) ? sums[t - off] : 0;
    __syncthreads();
    sums[t] += v;
    __syncthreads();
  }
  int run = (t == 0) ? 0 : sums[t - 1];
  for (int i = 0; i < PER; ++i) {
    int idx = base + i;
    if (idx < N_NODES) {
      run += deg[idx];
      rowptr[idx + 1] = run;
    }
  }
  if (t == 0) rowptr[0] = 0;
}

__global__ void scatter_edges(const int* __restrict__ ei, const int* __restrict__ rowptr,
                              int* __restrict__ fill, int* __restrict__ colsrc,
                              int* __restrict__ coldst) {
  int e = blockIdx.x * blockDim.x + threadIdx.x;
  if (e >= NET) return;
  int s, d;
  if (e < NE) { s = ei[e]; d = ei[NE + e]; }
  else        { s = e - NE; d = s; }
  int pos = atomicAdd(&fill[d], 1);
  int slot = rowptr[d] + pos;
  colsrc[slot] = s;
  coldst[slot] = d;
}

// ---------------- fp32 tiled GEMM: C[M,NCOL] = A[M,K] @ B[K,NCOL] ----------------

template<int K, int NCOL>
__global__ __launch_bounds__(256) void gemm_tile(const float* __restrict__ A,
                                                 const float* __restrict__ B,
                                                 float* __restrict__ C) {
  __shared__ float As[32][68];
  __shared__ float Bs[32][64];
  const int tid = threadIdx.x;
  const int tx = tid & 15;
  const int ty = tid >> 4;
  const int row0 = blockIdx.y * 64;
  const int col0 = blockIdx.x * 64;
  float acc[4][4] = {};

  for (int k0 = 0; k0 < K; k0 += 32) {
#pragma unroll
    for (int i = 0; i < 8; ++i) {
      int idx = tid + i * 256;
      int m = idx >> 5, k = idx & 31;
      int row = row0 + m;
      As[k][m] = (row < N_NODES) ? A[(size_t)row * K + k0 + k] : 0.f;
    }
#pragma unroll
    for (int i = 0; i < 8; ++i) {
      int idx = tid + i * 256;
      int kb = idx >> 6, c = idx & 63;
      Bs[kb][c] = B[(size_t)(k0 + kb) * NCOL + col0 + c];
    }
    __syncthreads();
#pragma unroll
    for (int kk = 0; kk < 32; ++kk) {
      float4 av = *(const float4*)&As[kk][ty * 4];
      float4 bv = *(const float4*)&Bs[kk][tx * 4];
      acc[0][0] = fmaf(av.x, bv.x, acc[0][0]);
      acc[0][1] = fmaf(av.x, bv.y, acc[0][1]);
      acc[0][2] = fmaf(av.x, bv.z, acc[0][2]);
      acc[0][3] = fmaf(av.x, bv.w, acc[0][3]);
      acc[1][0] = fmaf(av.y, bv.x, acc[1][0]);
      acc[1][1] = fmaf(av.y, bv.y, acc[1][1]);
      acc[1][2] = fmaf(av.y, bv.z, acc[1][2]);
      acc[1][3] = fmaf(av.y, bv.w, acc[1][3]);
      acc[2][0] = fmaf(av.z, bv.x, acc[2][0]);
      acc[2][1] = fmaf(av.z, bv.y, acc[2][1]);
      acc[2][2] = fmaf(av.z, bv.z, acc[2][2]);
      acc[2][3] = fmaf(av.z, bv.w, acc[2][3]);
      acc[3][0] = fmaf(av.w, bv.x, acc[3][0]);
      acc[3][1] = fmaf(av.w, bv.y, acc[3][1]);
      acc[3][2] = fmaf(av.w, bv.z, acc[3][2]);
      acc[3][3] = fmaf(av.w, bv.w, acc[3][3]);
    }
    __syncthreads();
  }
#pragma unroll
  for (int i = 0; i < 4; ++i) {
    int row = row0 + ty * 4 + i;
    if (row < N_NODES) {
      float4 v = make_float4(acc[i][0], acc[i][1], acc[i][2], acc[i][3]);
      *(float4*)&C[(size_t)row * NCOL + col0 + tx * 4] = v;
    }
  }
}

// ---------------- attention logits ----------------

__global__ __launch_bounds__(256) void al_heads(const float* __restrict__ H,
                                                const float* __restrict__ a_s,
                                                const float* __restrict__ a_d,
                                                float* __restrict__ als,
                                                float* __restrict__ ald) {
  int n = blockIdx.x;
  int tid = threadIdx.x;
  int h = tid >> 6, lane = tid & 63;
  float v = H[(size_t)n * C1 + tid];
  float ps = v * a_s[tid], pd = v * a_d[tid];
#pragma unroll
  for (int off = 32; off; off >>= 1) {
    ps += __shfl_down(ps, off, 64);
    pd += __shfl_down(pd, off, 64);
  }
  if (lane == 0) { als[n * HEADS + h] = ps; ald[n * HEADS + h] = pd; }
}

__global__ __launch_bounds__(256) void al_single(const float* __restrict__ H2,
                                                 const float* __restrict__ a_s,
                                                 const float* __restrict__ a_d,
                                                 float* __restrict__ als,
                                                 float* __restrict__ ald) {
  int wave = threadIdx.x >> 6, lane = threadIdx.x & 63;
  int n = blockIdx.x * 4 + wave;
  if (n >= N_NODES) return;
  float v0 = H2[(size_t)n * F_OUT + lane];
  float v1 = H2[(size_t)n * F_OUT + 64 + lane];
  float ps = v0 * a_s[lane] + v1 * a_s[64 + lane];
  float pd = v0 * a_d[lane] + v1 * a_d[64 + lane];
#pragma unroll
  for (int off = 32; off; off >>= 1) {
    ps += __shfl_down(ps, off, 64);
    pd += __shfl_down(pd, off, 64);
  }
  if (lane == 0) { als[n] = ps; ald[n] = pd; }
}

// ---------------- edge-parallel softmax numerators ----------------
// P stored head-planar: P[h*NET + slot]. No max-subtraction: scores ~N(0,1.3),
// exp cannot overflow fp32; result mathematically identical to reference.

__global__ void scores1(const int* __restrict__ colsrc, const int* __restrict__ coldst,
                        const float* __restrict__ als, const float* __restrict__ ald,
                        float* __restrict__ P) {
  int i = blockIdx.x * blockDim.x + threadIdx.x;
  if (i >= NET) return;
  int s = colsrc[i], d = coldst[i];
  float4 as = *(const float4*)&als[s * 4];
  float4 ad = *(const float4*)&ald[d * 4];
  float sc;
  sc = as.x + ad.x; sc = sc > 0.f ? sc : NEG_SLOPE * sc; P[0 * (size_t)NET + i] = __expf(sc);
  sc = as.y + ad.y; sc = sc > 0.f ? sc : NEG_SLOPE * sc; P[1 * (size_t)NET + i] = __expf(sc);
  sc = as.z + ad.z; sc = sc > 0.f ? sc : NEG_SLOPE * sc; P[2 * (size_t)NET + i] = __expf(sc);
  sc = as.w + ad.w; sc = sc > 0.f ? sc : NEG_SLOPE * sc; P[3 * (size_t)NET + i] = __expf(sc);
}

__global__ void scores2(const int* __restrict__ colsrc, const int* __restrict__ coldst,
                        const float* __restrict__ als, const float* __restrict__ ald,
                        float* __restrict__ P) {
  int i = blockIdx.x * blockDim.x + threadIdx.x;
  if (i >= NET) return;
  float sc = als[colsrc[i]] + ald[coldst[i]];
  sc = sc > 0.f ? sc : NEG_SLOPE * sc;
  P[i] = __expf(sc);
}

// ---------------- per-node denominators (inverse) ----------------

__global__ __launch_bounds__(256) void norm1(const int* __restrict__ rowptr,
                                             const float* __restrict__ P,
                                             float* __restrict__ sinv) {
  int wave = threadIdx.x >> 6, lane = threadIdx.x & 63;
  int n = blockIdx.x * 4 + wave;
  if (n >= N_NODES) return;
  int beg = rowptr[n], end = rowptr[n + 1];
  float s0 = 0.f, s1 = 0.f, s2 = 0.f, s3 = 0.f;
  for (int i = beg + lane; i < end; i += 64) {
    s0 += P[0 * (size_t)NET + i];
    s1 += P[1 * (size_t)NET + i];
    s2 += P[2 * (size_t)NET + i];
    s3 += P[3 * (size_t)NET + i];
  }
#pragma unroll
  for (int off = 32; off; off >>= 1) {
    s0 += __shfl_down(s0, off, 64);
    s1 += __shfl_down(s1, off, 64);
    s2 += __shfl_down(s2, off, 64);
    s3 += __shfl_down(s3, off, 64);
  }
  if (lane == 0) {
    float4 r = make_float4(1.f / s0, 1.f / s1, 1.f / s2, 1.f / s3);
    *(float4*)&sinv[n * 4] = r;
  }
}

__global__ __launch_bounds__(256) void norm2(const int* __restrict__ rowptr,
                                             const float* __restrict__ P,
                                             float* __restrict__ sinv) {
  int wave = threadIdx.x >> 6, lane = threadIdx.x & 63;
  int n = blockIdx.x * 4 + wave;
  if (n >= N_NODES) return;
  int beg = rowptr[n], end = rowptr[n + 1];
  float s = 0.f;
  for (int i = beg + lane; i < end; i += 64) s += P[i];
#pragma unroll
  for (int off = 32; off; off >>= 1) s += __shfl_down(s, off, 64);
  if (lane == 0) sinv[n] = 1.f / s;
}

// ---------------- weighted gather aggregation ----------------
// layer1: block = node, wave = head, lane = channel. No loop-carried rescale ->
// unroll 4 with independent accumulators, 4 gathers in flight.

__global__ __launch_bounds__(256) void agg1(const int* __restrict__ rowptr,
                                            const int* __restrict__ colsrc,
                                            const float* __restrict__ H,
                                            const float* __restrict__ P,
                                            const float* __restrict__ sinv,
                                            const float* __restrict__ b1,
                                            float* __restrict__ X2) {
  int n = blockIdx.x;
  int h = threadIdx.x >> 6;
  int lane = threadIdx.x & 63;
  int beg = rowptr[n], end = rowptr[n + 1];
  const float* __restrict__ Ph = P + (size_t)h * NET;
  float a0 = 0.f, a1 = 0.f, a2 = 0.f, a3 = 0.f;
  int i = beg;
  for (; i + 4 <= end; i += 4) {
    int s0 = colsrc[i], s1 = colsrc[i + 1], s2 = colsrc[i + 2], s3 = colsrc[i + 3];
    float w0 = Ph[i], w1 = Ph[i + 1], w2 = Ph[i + 2], w3 = Ph[i + 3];
    a0 = fmaf(w0, H[(size_t)s0 * C1 + h * HIDC + lane], a0);
    a1 = fmaf(w1, H[(size_t)s1 * C1 + h * HIDC + lane], a1);
    a2 = fmaf(w2, H[(size_t)s2 * C1 + h * HIDC + lane], a2);
    a3 = fmaf(w3, H[(size_t)s3 * C1 + h * HIDC + lane], a3);
  }
  for (; i < end; ++i) {
    a0 = fmaf(Ph[i], H[(size_t)colsrc[i] * C1 + h * HIDC + lane], a0);
  }
  float acc = (a0 + a1) + (a2 + a3);
  float o = acc * sinv[n * 4 + h] + b1[h * HIDC + lane];
  X2[(size_t)n * C1 + h * HIDC + lane] = fmaxf(o, 0.f);
}

// layer2: wave per node (4/block), lane covers c and c+64. Unroll 2 -> 4 gathers in flight.
__global__ __launch_bounds__(256) void agg2(const int* __restrict__ rowptr,
                                            const int* __restrict__ colsrc,
                                            const float* __restrict__ H2,
                                            const float* __restrict__ P,
                                            const float* __restrict__ sinv,
                                            const float* __restrict__ b2,
                                            float* __restrict__ out) {
  int wave = threadIdx.x >> 6, lane = threadIdx.x & 63;
  int n = blockIdx.x * 4 + wave;
  if (n >= N_NODES) return;
  int beg = rowptr[n], end = rowptr[n + 1];
  float a00 = 0.f, a01 = 0.f, a10 = 0.f, a11 = 0.f;
  int i = beg;
  for (; i + 2 <= end; i += 2) {
    int s0 = colsrc[i], s1 = colsrc[i + 1];
    float w0 = P[i], w1 = P[i + 1];
    a00 = fmaf(w0, H2[(size_t)s0 * F_OUT + lane], a00);
    a01 = fmaf(w0, H2[(size_t)s0 * F_OUT + 64 + lane], a01);
    a10 = fmaf(w1, H2[(size_t)s1 * F_OUT + lane], a10);
    a11 = fmaf(w1, H2[(size_t)s1 * F_OUT + 64 + lane], a11);
  }
  for (; i < end; ++i) {
    int s0 = colsrc[i];
    float w0 = P[i];
    a00 = fmaf(w0, H2[(size_t)s0 * F_OUT + lane], a00);
    a01 = fmaf(w0, H2[(size_t)s0 * F_OUT + 64 + lane], a01);
  }
  float si = sinv[n];
  out[(size_t)n * F_OUT + lane] = (a00 + a10) * si + b2[lane];
  out[(size_t)n * F_OUT + 64 + lane] = (a01 + a11) * si + b2[64 + lane];
}

// ---------------- launch ----------------

extern "C" void kernel_launch(void* const* d_in, const int* in_sizes, int n_in,
                              void* d_out, int out_size, void* d_ws, size_t ws_size,
                              hipStream_t stream) {
  const float* X   = (const float*)d_in[0];
  const int*   EI  = (const int*)d_in[1];
  const float* W1  = (const float*)d_in[2];
  const float* a1s = (const float*)d_in[3];
  const float* a1d = (const float*)d_in[4];
  const float* b1  = (const float*)d_in[5];
  const float* W2  = (const float*)d_in[6];
  const float* a2s = (const float*)d_in[7];
  const float* a2d = (const float*)d_in[8];
  const float* b2  = (const float*)d_in[9];
  float* out = (float*)d_out;

  char* ws = (char*)d_ws;
  size_t off = 0;
  auto alloc = [&](size_t bytes) -> void* {
    void* p = ws + off;
    off += (bytes + 255) & ~(size_t)255;
    return p;
  };
  int* deg     = (int*)alloc((size_t)N_NODES * 4);
  int* fill    = (int*)alloc((size_t)N_NODES * 4);
  int* rowptr  = (int*)alloc((size_t)(N_NODES + 1) * 4);
  int* colsrc  = (int*)alloc((size_t)NET * 4);
  int* coldst  = (int*)alloc((size_t)NET * 4);
  float* H1    = (float*)alloc((size_t)N_NODES * C1 * 4);   // reused as H2 later
  float* ALS1  = (float*)alloc((size_t)N_NODES * HEADS * 4);
  float* ALD1  = (float*)alloc((size_t)N_NODES * HEADS * 4);
  float* SINV1 = (float*)alloc((size_t)N_NODES * HEADS * 4);
  float* P1    = (float*)alloc((size_t)NET * HEADS * 4);    // reused as P2 later
  float* X2    = (float*)alloc((size_t)N_NODES * C1 * 4);
  float* ALS2  = (float*)alloc((size_t)N_NODES * 4);
  float* ALD2  = (float*)alloc((size_t)N_NODES * 4);
  float* SINV2 = (float*)alloc((size_t)N_NODES * 4);
  float* H2 = H1;   // H1 dead after agg1
  float* P2 = P1;   // P1 dead after agg1

  hipMemsetAsync(deg, 0, (size_t)N_NODES * 4, stream);
  hipMemsetAsync(fill, 0, (size_t)N_NODES * 4, stream);

  count_deg<<<(NET + 255) / 256, 256, 0, stream>>>(EI, deg);
  scan_rowptr<<<1, 1024, 0, stream>>>(deg, rowptr);
  scatter_edges<<<(NET + 255) / 256, 256, 0, stream>>>(EI, rowptr, fill, colsrc, coldst);

  // layer 1
  {
    dim3 grid(C1 / 64, (N_NODES + 63) / 64);
    gemm_tile<F_IN, C1><<<grid, 256, 0, stream>>>(X, W1, H1);
  }
  al_heads<<<N_NODES, 256, 0, stream>>>(H1, a1s, a1d, ALS1, ALD1);
  scores1<<<(NET + 255) / 256, 256, 0, stream>>>(colsrc, coldst, ALS1, ALD1, P1);
  norm1<<<(N_NODES + 3) / 4, 256, 0, stream>>>(rowptr, P1, SINV1);
  agg1<<<N_NODES, 256, 0, stream>>>(rowptr, colsrc, H1, P1, SINV1, b1, X2);

  // layer 2
  {
    dim3 grid(F_OUT / 64, (N_NODES + 63) / 64);
    gemm_tile<C1, F_OUT><<<grid, 256, 0, stream>>>(X2, W2, H2);
  }
  al_single<<<(N_NODES + 3) / 4, 256, 0, stream>>>(H2, a2s, a2d, ALS2, ALD2);
  scores2<<<(NET + 255) / 256, 256, 0, stream>>>(colsrc, coldst, ALS2, ALD2, P2);
  norm2<<<(N_NODES + 3) / 4, 256, 0, stream>>>(rowptr, P2, SINV2);
  agg2<<<(N_NODES + 3) / 4, 256, 0, stream>>>(rowptr, colsrc, H2, P2, SINV2, b2, out);
}

// Round 3
// 459.074 us; speedup vs baseline: 1.3920x; 1.2438x over previous
//
#include <hip/hip_runtime.h>
#include <math.h>

#define N_NODES 50000
#define F_IN    128
#define HIDC    64
#define HEADS   4
#define C1      (HEADS*HIDC)   // 256
#define F_OUT   128
#define NE      800000
#define NET     (NE + N_NODES) // 850000 edges incl self-loops
#define NEG_SLOPE 0.2f

typedef unsigned short ushort_t;

__device__ __forceinline__ float b2f(ushort_t x) {
  return __uint_as_float(((unsigned int)x) << 16);
}
__device__ __forceinline__ ushort_t f2bf(float f) {  // RNE, no NaN expected
  unsigned int u = __float_as_uint(f);
  return (ushort_t)((u + 0x7fffu + ((u >> 16) & 1u)) >> 16);
}

// ---------------- CSR build ----------------

__global__ void count_deg(const int* __restrict__ ei, int* __restrict__ deg) {
  int e = blockIdx.x * blockDim.x + threadIdx.x;
  if (e >= NET) return;
  int d = (e < NE) ? ei[NE + e] : (e - NE);
  atomicAdd(&deg[d], 1);
}

__global__ __launch_bounds__(1024) void scan_rowptr(const int* __restrict__ deg,
                                                    int* __restrict__ rowptr) {
  __shared__ int sums[1024];
  int t = threadIdx.x;
  const int PER = (N_NODES + 1023) / 1024;  // 49
  int base = t * PER;
  int s = 0;
  for (int i = 0; i < PER; ++i) {
    int idx = base + i;
    if (idx < N_NODES) s += deg[idx];
  }
  sums[t] = s;
  __syncthreads();
  for (int off = 1; off < 1024; off <<= 1) {
    int v = (t >= off) ? sums[t - off] : 0;
    __syncthreads();
    sums[t] += v;
    __syncthreads();
  }
  int run = (t == 0) ? 0 : sums[t - 1];
  for (int i = 0; i < PER; ++i) {
    int idx = base + i;
    if (idx < N_NODES) {
      run += deg[idx];
      rowptr[idx + 1] = run;
    }
  }
  if (t == 0) rowptr[0] = 0;
}

__global__ void scatter_edges(const int* __restrict__ ei, const int* __restrict__ rowptr,
                              int* __restrict__ fill, int* __restrict__ colsrc,
                              int* __restrict__ coldst) {
  int e = blockIdx.x * blockDim.x + threadIdx.x;
  if (e >= NET) return;
  int s, d;
  if (e < NE) { s = ei[e]; d = ei[NE + e]; }
  else        { s = e - NE; d = s; }
  int pos = atomicAdd(&fill[d], 1);
  int slot = rowptr[d] + pos;
  colsrc[slot] = s;
  coldst[slot] = d;
}

// ---------------- fp32 GEMM -> bf16 C, fused attention-logit dots ----------------
// AL_MODE 1: NCOL=256, col-tile == head -> direct store als/ald[row*4+h]
// AL_MODE 2: NCOL=128, head spans 2 col-tiles -> 2 commutative atomicAdds (deterministic)

template<int K, int NCOL, int AL_MODE>
__global__ __launch_bounds__(256) void gemm_bf16(const float* __restrict__ A,
                                                 const float* __restrict__ B,
                                                 ushort_t* __restrict__ Cb,
                                                 const float* __restrict__ a_s,
                                                 const float* __restrict__ a_d,
                                                 float* __restrict__ als,
                                                 float* __restrict__ ald) {
  __shared__ float As[32][68];
  __shared__ float Bs[32][64];
  const int tid = threadIdx.x;
  const int tx = tid & 15;
  const int ty = tid >> 4;
  const int row0 = blockIdx.y * 64;
  const int col0 = blockIdx.x * 64;
  float acc[4][4] = {};

  for (int k0 = 0; k0 < K; k0 += 32) {
#pragma unroll
    for (int i = 0; i < 8; ++i) {
      int idx = tid + i * 256;
      int m = idx >> 5, k = idx & 31;
      int row = row0 + m;
      As[k][m] = (row < N_NODES) ? A[(size_t)row * K + k0 + k] : 0.f;
    }
#pragma unroll
    for (int i = 0; i < 8; ++i) {
      int idx = tid + i * 256;
      int kb = idx >> 6, c = idx & 63;
      Bs[kb][c] = B[(size_t)(k0 + kb) * NCOL + col0 + c];
    }
    __syncthreads();
#pragma unroll
    for (int kk = 0; kk < 32; ++kk) {
      float4 av = *(const float4*)&As[kk][ty * 4];
      float4 bv = *(const float4*)&Bs[kk][tx * 4];
      acc[0][0] = fmaf(av.x, bv.x, acc[0][0]);
      acc[0][1] = fmaf(av.x, bv.y, acc[0][1]);
      acc[0][2] = fmaf(av.x, bv.z, acc[0][2]);
      acc[0][3] = fmaf(av.x, bv.w, acc[0][3]);
      acc[1][0] = fmaf(av.y, bv.x, acc[1][0]);
      acc[1][1] = fmaf(av.y, bv.y, acc[1][1]);
      acc[1][2] = fmaf(av.y, bv.z, acc[1][2]);
      acc[1][3] = fmaf(av.y, bv.w, acc[1][3]);
      acc[2][0] = fmaf(av.z, bv.x, acc[2][0]);
      acc[2][1] = fmaf(av.z, bv.y, acc[2][1]);
      acc[2][2] = fmaf(av.z, bv.z, acc[2][2]);
      acc[2][3] = fmaf(av.z, bv.w, acc[2][3]);
      acc[3][0] = fmaf(av.w, bv.x, acc[3][0]);
      acc[3][1] = fmaf(av.w, bv.y, acc[3][1]);
      acc[3][2] = fmaf(av.w, bv.z, acc[3][2]);
      acc[3][3] = fmaf(av.w, bv.w, acc[3][3]);
    }
    __syncthreads();
  }

#pragma unroll
  for (int i = 0; i < 4; ++i) {
    int row = row0 + ty * 4 + i;
    if (row < N_NODES) {
      ushort4 o;
      o.x = f2bf(acc[i][0]); o.y = f2bf(acc[i][1]);
      o.z = f2bf(acc[i][2]); o.w = f2bf(acc[i][3]);
      *(ushort4*)&Cb[(size_t)row * NCOL + col0 + tx * 4] = o;
    }
  }

  if (AL_MODE) {
    float4 asv = *(const float4*)&a_s[col0 + tx * 4];
    float4 adv = *(const float4*)&a_d[col0 + tx * 4];
#pragma unroll
    for (int i = 0; i < 4; ++i) {
      float ps = acc[i][0] * asv.x + acc[i][1] * asv.y + acc[i][2] * asv.z + acc[i][3] * asv.w;
      float pd = acc[i][0] * adv.x + acc[i][1] * adv.y + acc[i][2] * adv.z + acc[i][3] * adv.w;
#pragma unroll
      for (int m = 8; m; m >>= 1) {
        ps += __shfl_xor(ps, m);
        pd += __shfl_xor(pd, m);
      }
      int row = row0 + ty * 4 + i;
      if (tx == 0 && row < N_NODES) {
        if (AL_MODE == 1) {
          int h = col0 >> 6;
          als[row * 4 + h] = ps;
          ald[row * 4 + h] = pd;
        } else {
          atomicAdd(&als[row], ps);
          atomicAdd(&ald[row], pd);
        }
      }
    }
  }
}

// ---------------- edge-parallel softmax numerators ----------------
// Layer1 P interleaved [NET][4]. No max-subtraction: scores ~N(0,~1), exp safe in fp32.

__global__ void scores1(const int* __restrict__ colsrc, const int* __restrict__ coldst,
                        const float* __restrict__ als, const float* __restrict__ ald,
                        float* __restrict__ P) {
  int i = blockIdx.x * blockDim.x + threadIdx.x;
  if (i >= NET) return;
  int s = colsrc[i], d = coldst[i];
  float4 as = *(const float4*)&als[s * 4];
  float4 ad = *(const float4*)&ald[d * 4];
  float4 p;
  float sc;
  sc = as.x + ad.x; sc = sc > 0.f ? sc : NEG_SLOPE * sc; p.x = __expf(sc);
  sc = as.y + ad.y; sc = sc > 0.f ? sc : NEG_SLOPE * sc; p.y = __expf(sc);
  sc = as.z + ad.z; sc = sc > 0.f ? sc : NEG_SLOPE * sc; p.z = __expf(sc);
  sc = as.w + ad.w; sc = sc > 0.f ? sc : NEG_SLOPE * sc; p.w = __expf(sc);
  *(float4*)&P[(size_t)i * 4] = p;
}

__global__ void scores2(const int* __restrict__ colsrc, const int* __restrict__ coldst,
                        const float* __restrict__ als, const float* __restrict__ ald,
                        float* __restrict__ P) {
  int i = blockIdx.x * blockDim.x + threadIdx.x;
  if (i >= NET) return;
  float sc = als[colsrc[i]] + ald[coldst[i]];
  sc = sc > 0.f ? sc : NEG_SLOPE * sc;
  P[i] = __expf(sc);
}

// ---------------- per-node denominators (inverse) ----------------

__global__ __launch_bounds__(256) void norm1(const int* __restrict__ rowptr,
                                             const float* __restrict__ P,
                                             float* __restrict__ sinv) {
  int wave = threadIdx.x >> 6, lane = threadIdx.x & 63;
  int n = blockIdx.x * 4 + wave;
  if (n >= N_NODES) return;
  int beg = rowptr[n], end = rowptr[n + 1];
  float s0 = 0.f, s1 = 0.f, s2 = 0.f, s3 = 0.f;
  for (int i = beg + lane; i < end; i += 64) {
    float4 p = *(const float4*)&P[(size_t)i * 4];
    s0 += p.x; s1 += p.y; s2 += p.z; s3 += p.w;
  }
#pragma unroll
  for (int off = 32; off; off >>= 1) {
    s0 += __shfl_down(s0, off, 64);
    s1 += __shfl_down(s1, off, 64);
    s2 += __shfl_down(s2, off, 64);
    s3 += __shfl_down(s3, off, 64);
  }
  if (lane == 0) {
    float4 r = make_float4(1.f / s0, 1.f / s1, 1.f / s2, 1.f / s3);
    *(float4*)&sinv[n * 4] = r;
  }
}

__global__ __launch_bounds__(256) void norm2(const int* __restrict__ rowptr,
                                             const float* __restrict__ P,
                                             float* __restrict__ sinv) {
  int wave = threadIdx.x >> 6, lane = threadIdx.x & 63;
  int n = blockIdx.x * 4 + wave;
  if (n >= N_NODES) return;
  int beg = rowptr[n], end = rowptr[n + 1];
  float s = 0.f;
  for (int i = beg + lane; i < end; i += 64) s += P[i];
#pragma unroll
  for (int off = 32; off; off >>= 1) s += __shfl_down(s, off, 64);
  if (lane == 0) sinv[n] = 1.f / s;
}

// ---------------- weighted gather aggregation (bf16 messages) ----------------
// layer1: wave per node; lane covers 4 channels (256 total); 512B coalesced row read/edge.

__global__ __launch_bounds__(256) void agg1(const int* __restrict__ rowptr,
                                            const int* __restrict__ colsrc,
                                            const ushort_t* __restrict__ Hb,
                                            const float* __restrict__ P,
                                            const float* __restrict__ sinv,
                                            const float* __restrict__ b1,
                                            float* __restrict__ X2) {
  int wave = threadIdx.x >> 6, lane = threadIdx.x & 63;
  int n = blockIdx.x * 4 + wave;
  if (n >= N_NODES) return;
  int h = lane >> 4;  // lane*4 / 64
  int beg = rowptr[n], end = rowptr[n + 1];
  float4 a0 = {0, 0, 0, 0}, a1 = a0, a2 = a0, a3 = a0;
  int i = beg;
  for (; i + 4 <= end; i += 4) {
    int s0 = colsrc[i], s1 = colsrc[i + 1], s2 = colsrc[i + 2], s3 = colsrc[i + 3];
    float w0 = P[(size_t)i * 4 + h];
    float w1 = P[(size_t)(i + 1) * 4 + h];
    float w2 = P[(size_t)(i + 2) * 4 + h];
    float w3 = P[(size_t)(i + 3) * 4 + h];
    ushort4 v0 = *(const ushort4*)&Hb[(size_t)s0 * C1 + lane * 4];
    ushort4 v1 = *(const ushort4*)&Hb[(size_t)s1 * C1 + lane * 4];
    ushort4 v2 = *(const ushort4*)&Hb[(size_t)s2 * C1 + lane * 4];
    ushort4 v3 = *(const ushort4*)&Hb[(size_t)s3 * C1 + lane * 4];
    a0.x = fmaf(w0, b2f(v0.x), a0.x); a0.y = fmaf(w0, b2f(v0.y), a0.y);
    a0.z = fmaf(w0, b2f(v0.z), a0.z); a0.w = fmaf(w0, b2f(v0.w), a0.w);
    a1.x = fmaf(w1, b2f(v1.x), a1.x); a1.y = fmaf(w1, b2f(v1.y), a1.y);
    a1.z = fmaf(w1, b2f(v1.z), a1.z); a1.w = fmaf(w1, b2f(v1.w), a1.w);
    a2.x = fmaf(w2, b2f(v2.x), a2.x); a2.y = fmaf(w2, b2f(v2.y), a2.y);
    a2.z = fmaf(w2, b2f(v2.z), a2.z); a2.w = fmaf(w2, b2f(v2.w), a2.w);
    a3.x = fmaf(w3, b2f(v3.x), a3.x); a3.y = fmaf(w3, b2f(v3.y), a3.y);
    a3.z = fmaf(w3, b2f(v3.z), a3.z); a3.w = fmaf(w3, b2f(v3.w), a3.w);
  }
  for (; i < end; ++i) {
    int s0 = colsrc[i];
    float w0 = P[(size_t)i * 4 + h];
    ushort4 v0 = *(const ushort4*)&Hb[(size_t)s0 * C1 + lane * 4];
    a0.x = fmaf(w0, b2f(v0.x), a0.x); a0.y = fmaf(w0, b2f(v0.y), a0.y);
    a0.z = fmaf(w0, b2f(v0.z), a0.z); a0.w = fmaf(w0, b2f(v0.w), a0.w);
  }
  float ax = (a0.x + a1.x) + (a2.x + a3.x);
  float ay = (a0.y + a1.y) + (a2.y + a3.y);
  float az = (a0.z + a1.z) + (a2.z + a3.z);
  float aw = (a0.w + a1.w) + (a2.w + a3.w);
  float si = sinv[n * 4 + h];
  int c = lane * 4;
  float4 bb = *(const float4*)&b1[c];
  float4 o;
  o.x = fmaxf(ax * si + bb.x, 0.f);
  o.y = fmaxf(ay * si + bb.y, 0.f);
  o.z = fmaxf(az * si + bb.z, 0.f);
  o.w = fmaxf(aw * si + bb.w, 0.f);
  *(float4*)&X2[(size_t)n * C1 + c] = o;
}

// layer2: wave per node; lane covers 2 channels (128 total); 256B row read/edge.
__global__ __launch_bounds__(256) void agg2(const int* __restrict__ rowptr,
                                            const int* __restrict__ colsrc,
                                            const ushort_t* __restrict__ Hb,
                                            const float* __restrict__ P,
                                            const float* __restrict__ sinv,
                                            const float* __restrict__ b2,
                                            float* __restrict__ out) {
  int wave = threadIdx.x >> 6, lane = threadIdx.x & 63;
  int n = blockIdx.x * 4 + wave;
  if (n >= N_NODES) return;
  int beg = rowptr[n], end = rowptr[n + 1];
  float ax0 = 0.f, ax1 = 0.f, ax2 = 0.f, ax3 = 0.f;
  float ay0 = 0.f, ay1 = 0.f, ay2 = 0.f, ay3 = 0.f;
  int i = beg;
  for (; i + 4 <= end; i += 4) {
    int s0 = colsrc[i], s1 = colsrc[i + 1], s2 = colsrc[i + 2], s3 = colsrc[i + 3];
    float w0 = P[i], w1 = P[i + 1], w2 = P[i + 2], w3 = P[i + 3];
    ushort2 v0 = *(const ushort2*)&Hb[(size_t)s0 * F_OUT + lane * 2];
    ushort2 v1 = *(const ushort2*)&Hb[(size_t)s1 * F_OUT + lane * 2];
    ushort2 v2 = *(const ushort2*)&Hb[(size_t)s2 * F_OUT + lane * 2];
    ushort2 v3 = *(const ushort2*)&Hb[(size_t)s3 * F_OUT + lane * 2];
    ax0 = fmaf(w0, b2f(v0.x), ax0); ay0 = fmaf(w0, b2f(v0.y), ay0);
    ax1 = fmaf(w1, b2f(v1.x), ax1); ay1 = fmaf(w1, b2f(v1.y), ay1);
    ax2 = fmaf(w2, b2f(v2.x), ax2); ay2 = fmaf(w2, b2f(v2.y), ay2);
    ax3 = fmaf(w3, b2f(v3.x), ax3); ay3 = fmaf(w3, b2f(v3.y), ay3);
  }
  for (; i < end; ++i) {
    int s0 = colsrc[i];
    float w0 = P[i];
    ushort2 v0 = *(const ushort2*)&Hb[(size_t)s0 * F_OUT + lane * 2];
    ax0 = fmaf(w0, b2f(v0.x), ax0); ay0 = fmaf(w0, b2f(v0.y), ay0);
  }
  float si = sinv[n];
  int c = lane * 2;
  float2 o;
  o.x = ((ax0 + ax1) + (ax2 + ax3)) * si + b2[c];
  o.y = ((ay0 + ay1) + (ay2 + ay3)) * si + b2[c + 1];
  *(float2*)&out[(size_t)n * F_OUT + c] = o;
}

// ---------------- launch ----------------

extern "C" void kernel_launch(void* const* d_in, const int* in_sizes, int n_in,
                              void* d_out, int out_size, void* d_ws, size_t ws_size,
                              hipStream_t stream) {
  const float* X   = (const float*)d_in[0];
  const int*   EI  = (const int*)d_in[1];
  const float* W1  = (const float*)d_in[2];
  const float* a1s = (const float*)d_in[3];
  const float* a1d = (const float*)d_in[4];
  const float* b1  = (const float*)d_in[5];
  const float* W2  = (const float*)d_in[6];
  const float* a2s = (const float*)d_in[7];
  const float* a2d = (const float*)d_in[8];
  const float* b2  = (const float*)d_in[9];
  float* out = (float*)d_out;

  char* ws = (char*)d_ws;
  size_t off = 0;
  auto alloc = [&](size_t bytes) -> void* {
    void* p = ws + off;
    off += (bytes + 255) & ~(size_t)255;
    return p;
  };
  int* deg        = (int*)alloc((size_t)N_NODES * 4);
  int* fill       = (int*)alloc((size_t)N_NODES * 4);
  int* rowptr     = (int*)alloc((size_t)(N_NODES + 1) * 4);
  int* colsrc     = (int*)alloc((size_t)NET * 4);
  int* coldst     = (int*)alloc((size_t)NET * 4);
  ushort_t* H1b   = (ushort_t*)alloc((size_t)N_NODES * C1 * 2);   // 25.6MB, reused as H2b
  float* ALS1     = (float*)alloc((size_t)N_NODES * HEADS * 4);
  float* ALD1     = (float*)alloc((size_t)N_NODES * HEADS * 4);
  float* SINV1    = (float*)alloc((size_t)N_NODES * HEADS * 4);
  float* P1       = (float*)alloc((size_t)NET * HEADS * 4);       // 13.6MB
  float* X2       = (float*)alloc((size_t)N_NODES * C1 * 4);      // 51.2MB
  float* ALS2     = (float*)alloc((size_t)N_NODES * 4);
  float* ALD2     = (float*)alloc((size_t)N_NODES * 4);
  float* SINV2    = (float*)alloc((size_t)N_NODES * 4);
  float* P2       = (float*)alloc((size_t)NET * 4);               // 3.4MB
  ushort_t* H2b = H1b;  // H1b dead after agg1; gemm2 runs after agg1 in stream order

  hipMemsetAsync(deg, 0, (size_t)N_NODES * 4, stream);
  hipMemsetAsync(fill, 0, (size_t)N_NODES * 4, stream);
  hipMemsetAsync(ALS2, 0, (size_t)N_NODES * 4, stream);   // atomic accumulators
  hipMemsetAsync(ALD2, 0, (size_t)N_NODES * 4, stream);

  count_deg<<<(NET + 255) / 256, 256, 0, stream>>>(EI, deg);
  scan_rowptr<<<1, 1024, 0, stream>>>(deg, rowptr);
  scatter_edges<<<(NET + 255) / 256, 256, 0, stream>>>(EI, rowptr, fill, colsrc, coldst);

  // layer 1
  {
    dim3 grid(C1 / 64, (N_NODES + 63) / 64);
    gemm_bf16<F_IN, C1, 1><<<grid, 256, 0, stream>>>(X, W1, H1b, a1s, a1d, ALS1, ALD1);
  }
  scores1<<<(NET + 255) / 256, 256, 0, stream>>>(colsrc, coldst, ALS1, ALD1, P1);
  norm1<<<(N_NODES + 3) / 4, 256, 0, stream>>>(rowptr, P1, SINV1);
  agg1<<<(N_NODES + 3) / 4, 256, 0, stream>>>(rowptr, colsrc, H1b, P1, SINV1, b1, X2);

  // layer 2
  {
    dim3 grid(F_OUT / 64, (N_NODES + 63) / 64);
    gemm_bf16<C1, F_OUT, 2><<<grid, 256, 0, stream>>>(X2, W2, H2b, a2s, a2d, ALS2, ALD2);
  }
  scores2<<<(NET + 255) / 256, 256, 0, stream>>>(colsrc, coldst, ALS2, ALD2, P2);
  norm2<<<(N_NODES + 3) / 4, 256, 0, stream>>>(rowptr, P2, SINV2);
  agg2<<<(N_NODES + 3) / 4, 256, 0, stream>>>(rowptr, colsrc, H2b, P2, SINV2, b2, out);
}

// Round 4
// 373.772 us; speedup vs baseline: 1.7097x; 1.2282x over previous
//
#include <hip/hip_runtime.h>
#include <math.h>

#define N_NODES 50000
#define F_IN    128
#define HIDC    64
#define HEADS   4
#define C1      (HEADS*HIDC)   // 256
#define F_OUT   128
#define NE      800000
#define NET     (NE + N_NODES) // 850000 edges incl self-loops
#define NEG_SLOPE 0.2f
#define SCAN_NBLKS ((N_NODES + 255) / 256)   // 196

typedef unsigned short ushort_t;

__device__ __forceinline__ float b2f(ushort_t x) {
  return __uint_as_float(((unsigned int)x) << 16);
}
__device__ __forceinline__ ushort_t f2bf(float f) {  // RNE, no NaN expected
  unsigned int u = __float_as_uint(f);
  return (ushort_t)((u + 0x7fffu + ((u >> 16) & 1u)) >> 16);
}
__device__ __forceinline__ float ldA(float v) { return v; }
__device__ __forceinline__ float ldA(ushort_t v) { return b2f(v); }

// ---------------- CSR build ----------------

__global__ void count_deg(const int* __restrict__ ei, int* __restrict__ deg) {
  int e = blockIdx.x * blockDim.x + threadIdx.x;
  if (e >= NET) return;
  int d = (e < NE) ? ei[NE + e] : (e - NE);
  atomicAdd(&deg[d], 1);
}

// Hierarchical scan: per-block inclusive scan of 256-elem chunks.
__global__ __launch_bounds__(256) void scan_blocks(const int* __restrict__ deg,
                                                   int* __restrict__ tmp,
                                                   int* __restrict__ bsum) {
  __shared__ int sh[256];
  int b = blockIdx.x, t = threadIdx.x;
  int idx = b * 256 + t;
  sh[t] = (idx < N_NODES) ? deg[idx] : 0;
  __syncthreads();
#pragma unroll
  for (int off = 1; off < 256; off <<= 1) {
    int u = (t >= off) ? sh[t - off] : 0;
    __syncthreads();
    sh[t] += u;
    __syncthreads();
  }
  if (idx < N_NODES) tmp[idx] = sh[t];
  if (t == 255) bsum[b] = sh[255];
}

// Scan the 196 block sums in one small block (inclusive, in place).
__global__ __launch_bounds__(256) void scan_bsum(int* __restrict__ bsum) {
  __shared__ int sh[256];
  int t = threadIdx.x;
  sh[t] = (t < SCAN_NBLKS) ? bsum[t] : 0;
  __syncthreads();
#pragma unroll
  for (int off = 1; off < 256; off <<= 1) {
    int u = (t >= off) ? sh[t - off] : 0;
    __syncthreads();
    sh[t] += u;
    __syncthreads();
  }
  if (t < SCAN_NBLKS) bsum[t] = sh[t];
}

__global__ __launch_bounds__(256) void finalize_rowptr(const int* __restrict__ tmp,
                                                       const int* __restrict__ bsum,
                                                       int* __restrict__ rowptr) {
  int b = blockIdx.x;
  int idx = b * 256 + threadIdx.x;
  if (idx == 0) rowptr[0] = 0;
  if (idx < N_NODES) {
    int off = (b == 0) ? 0 : bsum[b - 1];
    rowptr[idx + 1] = tmp[idx] + off;
  }
}

__global__ void scatter_edges(const int* __restrict__ ei, const int* __restrict__ rowptr,
                              int* __restrict__ fill, int* __restrict__ colsrc,
                              int* __restrict__ coldst) {
  int e = blockIdx.x * blockDim.x + threadIdx.x;
  if (e >= NET) return;
  int s, d;
  if (e < NE) { s = ei[e]; d = ei[NE + e]; }
  else        { s = e - NE; d = s; }
  int pos = atomicAdd(&fill[d], 1);
  int slot = rowptr[d] + pos;
  colsrc[slot] = s;
  coldst[slot] = d;
}

// ---------------- fp32-accum GEMM -> bf16 C, fused attention-logit dots ----------------
// AT = A element type (float or bf16-as-ushort).
// AL_MODE 1: NCOL=256, col-tile == head -> direct store als/ald[row*4+h]
// AL_MODE 2: NCOL=128, head spans 2 col-tiles -> 2 commutative atomicAdds (deterministic)

template<int K, int NCOL, int AL_MODE, typename AT>
__global__ __launch_bounds__(256) void gemm_bf16(const AT* __restrict__ A,
                                                 const float* __restrict__ B,
                                                 ushort_t* __restrict__ Cb,
                                                 const float* __restrict__ a_s,
                                                 const float* __restrict__ a_d,
                                                 float* __restrict__ als,
                                                 float* __restrict__ ald) {
  __shared__ float As[32][68];
  __shared__ float Bs[32][64];
  const int tid = threadIdx.x;
  const int tx = tid & 15;
  const int ty = tid >> 4;
  const int row0 = blockIdx.y * 64;
  const int col0 = blockIdx.x * 64;
  float acc[4][4] = {};

  for (int k0 = 0; k0 < K; k0 += 32) {
#pragma unroll
    for (int i = 0; i < 8; ++i) {
      int idx = tid + i * 256;
      int m = idx >> 5, k = idx & 31;
      int row = row0 + m;
      As[k][m] = (row < N_NODES) ? ldA(A[(size_t)row * K + k0 + k]) : 0.f;
    }
#pragma unroll
    for (int i = 0; i < 8; ++i) {
      int idx = tid + i * 256;
      int kb = idx >> 6, c = idx & 63;
      Bs[kb][c] = B[(size_t)(k0 + kb) * NCOL + col0 + c];
    }
    __syncthreads();
#pragma unroll
    for (int kk = 0; kk < 32; ++kk) {
      float4 av = *(const float4*)&As[kk][ty * 4];
      float4 bv = *(const float4*)&Bs[kk][tx * 4];
      acc[0][0] = fmaf(av.x, bv.x, acc[0][0]);
      acc[0][1] = fmaf(av.x, bv.y, acc[0][1]);
      acc[0][2] = fmaf(av.x, bv.z, acc[0][2]);
      acc[0][3] = fmaf(av.x, bv.w, acc[0][3]);
      acc[1][0] = fmaf(av.y, bv.x, acc[1][0]);
      acc[1][1] = fmaf(av.y, bv.y, acc[1][1]);
      acc[1][2] = fmaf(av.y, bv.z, acc[1][2]);
      acc[1][3] = fmaf(av.y, bv.w, acc[1][3]);
      acc[2][0] = fmaf(av.z, bv.x, acc[2][0]);
      acc[2][1] = fmaf(av.z, bv.y, acc[2][1]);
      acc[2][2] = fmaf(av.z, bv.z, acc[2][2]);
      acc[2][3] = fmaf(av.z, bv.w, acc[2][3]);
      acc[3][0] = fmaf(av.w, bv.x, acc[3][0]);
      acc[3][1] = fmaf(av.w, bv.y, acc[3][1]);
      acc[3][2] = fmaf(av.w, bv.z, acc[3][2]);
      acc[3][3] = fmaf(av.w, bv.w, acc[3][3]);
    }
    __syncthreads();
  }

#pragma unroll
  for (int i = 0; i < 4; ++i) {
    int row = row0 + ty * 4 + i;
    if (row < N_NODES) {
      ushort4 o;
      o.x = f2bf(acc[i][0]); o.y = f2bf(acc[i][1]);
      o.z = f2bf(acc[i][2]); o.w = f2bf(acc[i][3]);
      *(ushort4*)&Cb[(size_t)row * NCOL + col0 + tx * 4] = o;
    }
  }

  if (AL_MODE) {
    float4 asv = *(const float4*)&a_s[col0 + tx * 4];
    float4 adv = *(const float4*)&a_d[col0 + tx * 4];
#pragma unroll
    for (int i = 0; i < 4; ++i) {
      float ps = acc[i][0] * asv.x + acc[i][1] * asv.y + acc[i][2] * asv.z + acc[i][3] * asv.w;
      float pd = acc[i][0] * adv.x + acc[i][1] * adv.y + acc[i][2] * adv.z + acc[i][3] * adv.w;
#pragma unroll
      for (int m = 8; m; m >>= 1) {
        ps += __shfl_xor(ps, m);
        pd += __shfl_xor(pd, m);
      }
      int row = row0 + ty * 4 + i;
      if (tx == 0 && row < N_NODES) {
        if (AL_MODE == 1) {
          int h = col0 >> 6;
          als[row * 4 + h] = ps;
          ald[row * 4 + h] = pd;
        } else {
          atomicAdd(&als[row], ps);
          atomicAdd(&ald[row], pd);
        }
      }
    }
  }
}

// ---------------- edge-parallel softmax numerators ----------------
// Layer1 P interleaved [NET][4]. No max-subtraction: scores ~N(0,~1), exp safe in fp32.

__global__ void scores1(const int* __restrict__ colsrc, const int* __restrict__ coldst,
                        const float* __restrict__ als, const float* __restrict__ ald,
                        float* __restrict__ P) {
  int i = blockIdx.x * blockDim.x + threadIdx.x;
  if (i >= NET) return;
  int s = colsrc[i], d = coldst[i];
  float4 as = *(const float4*)&als[s * 4];
  float4 ad = *(const float4*)&ald[d * 4];
  float4 p;
  float sc;
  sc = as.x + ad.x; sc = sc > 0.f ? sc : NEG_SLOPE * sc; p.x = __expf(sc);
  sc = as.y + ad.y; sc = sc > 0.f ? sc : NEG_SLOPE * sc; p.y = __expf(sc);
  sc = as.z + ad.z; sc = sc > 0.f ? sc : NEG_SLOPE * sc; p.z = __expf(sc);
  sc = as.w + ad.w; sc = sc > 0.f ? sc : NEG_SLOPE * sc; p.w = __expf(sc);
  *(float4*)&P[(size_t)i * 4] = p;
}

__global__ void scores2(const int* __restrict__ colsrc, const int* __restrict__ coldst,
                        const float* __restrict__ als, const float* __restrict__ ald,
                        float* __restrict__ P) {
  int i = blockIdx.x * blockDim.x + threadIdx.x;
  if (i >= NET) return;
  float sc = als[colsrc[i]] + ald[coldst[i]];
  sc = sc > 0.f ? sc : NEG_SLOPE * sc;
  P[i] = __expf(sc);
}

// ---------------- per-node denominators (inverse) ----------------

__global__ __launch_bounds__(256) void norm1(const int* __restrict__ rowptr,
                                             const float* __restrict__ P,
                                             float* __restrict__ sinv) {
  int wave = threadIdx.x >> 6, lane = threadIdx.x & 63;
  int n = blockIdx.x * 4 + wave;
  if (n >= N_NODES) return;
  int beg = rowptr[n], end = rowptr[n + 1];
  float s0 = 0.f, s1 = 0.f, s2 = 0.f, s3 = 0.f;
  for (int i = beg + lane; i < end; i += 64) {
    float4 p = *(const float4*)&P[(size_t)i * 4];
    s0 += p.x; s1 += p.y; s2 += p.z; s3 += p.w;
  }
#pragma unroll
  for (int off = 32; off; off >>= 1) {
    s0 += __shfl_down(s0, off, 64);
    s1 += __shfl_down(s1, off, 64);
    s2 += __shfl_down(s2, off, 64);
    s3 += __shfl_down(s3, off, 64);
  }
  if (lane == 0) {
    float4 r = make_float4(1.f / s0, 1.f / s1, 1.f / s2, 1.f / s3);
    *(float4*)&sinv[n * 4] = r;
  }
}

__global__ __launch_bounds__(256) void norm2(const int* __restrict__ rowptr,
                                             const float* __restrict__ P,
                                             float* __restrict__ sinv) {
  int wave = threadIdx.x >> 6, lane = threadIdx.x & 63;
  int n = blockIdx.x * 4 + wave;
  if (n >= N_NODES) return;
  int beg = rowptr[n], end = rowptr[n + 1];
  float s = 0.f;
  for (int i = beg + lane; i < end; i += 64) s += P[i];
#pragma unroll
  for (int off = 32; off; off >>= 1) s += __shfl_down(s, off, 64);
  if (lane == 0) sinv[n] = 1.f / s;
}

// ---------------- weighted gather aggregation (bf16 messages) ----------------
// layer1: wave per node; lane covers 4 channels (256 total); 512B coalesced row read/edge.
// Output X2 stored bf16 (feeds gemm2's A operand).

__global__ __launch_bounds__(256) void agg1(const int* __restrict__ rowptr,
                                            const int* __restrict__ colsrc,
                                            const ushort_t* __restrict__ Hb,
                                            const float* __restrict__ P,
                                            const float* __restrict__ sinv,
                                            const float* __restrict__ b1,
                                            ushort_t* __restrict__ X2b) {
  int wave = threadIdx.x >> 6, lane = threadIdx.x & 63;
  int n = blockIdx.x * 4 + wave;
  if (n >= N_NODES) return;
  int h = lane >> 4;  // lane*4 / 64
  int beg = rowptr[n], end = rowptr[n + 1];
  float4 a0 = {0, 0, 0, 0}, a1 = a0, a2 = a0, a3 = a0;
  int i = beg;
  for (; i + 4 <= end; i += 4) {
    int s0 = colsrc[i], s1 = colsrc[i + 1], s2 = colsrc[i + 2], s3 = colsrc[i + 3];
    float w0 = P[(size_t)i * 4 + h];
    float w1 = P[(size_t)(i + 1) * 4 + h];
    float w2 = P[(size_t)(i + 2) * 4 + h];
    float w3 = P[(size_t)(i + 3) * 4 + h];
    ushort4 v0 = *(const ushort4*)&Hb[(size_t)s0 * C1 + lane * 4];
    ushort4 v1 = *(const ushort4*)&Hb[(size_t)s1 * C1 + lane * 4];
    ushort4 v2 = *(const ushort4*)&Hb[(size_t)s2 * C1 + lane * 4];
    ushort4 v3 = *(const ushort4*)&Hb[(size_t)s3 * C1 + lane * 4];
    a0.x = fmaf(w0, b2f(v0.x), a0.x); a0.y = fmaf(w0, b2f(v0.y), a0.y);
    a0.z = fmaf(w0, b2f(v0.z), a0.z); a0.w = fmaf(w0, b2f(v0.w), a0.w);
    a1.x = fmaf(w1, b2f(v1.x), a1.x); a1.y = fmaf(w1, b2f(v1.y), a1.y);
    a1.z = fmaf(w1, b2f(v1.z), a1.z); a1.w = fmaf(w1, b2f(v1.w), a1.w);
    a2.x = fmaf(w2, b2f(v2.x), a2.x); a2.y = fmaf(w2, b2f(v2.y), a2.y);
    a2.z = fmaf(w2, b2f(v2.z), a2.z); a2.w = fmaf(w2, b2f(v2.w), a2.w);
    a3.x = fmaf(w3, b2f(v3.x), a3.x); a3.y = fmaf(w3, b2f(v3.y), a3.y);
    a3.z = fmaf(w3, b2f(v3.z), a3.z); a3.w = fmaf(w3, b2f(v3.w), a3.w);
  }
  for (; i < end; ++i) {
    int s0 = colsrc[i];
    float w0 = P[(size_t)i * 4 + h];
    ushort4 v0 = *(const ushort4*)&Hb[(size_t)s0 * C1 + lane * 4];
    a0.x = fmaf(w0, b2f(v0.x), a0.x); a0.y = fmaf(w0, b2f(v0.y), a0.y);
    a0.z = fmaf(w0, b2f(v0.z), a0.z); a0.w = fmaf(w0, b2f(v0.w), a0.w);
  }
  float ax = (a0.x + a1.x) + (a2.x + a3.x);
  float ay = (a0.y + a1.y) + (a2.y + a3.y);
  float az = (a0.z + a1.z) + (a2.z + a3.z);
  float aw = (a0.w + a1.w) + (a2.w + a3.w);
  float si = sinv[n * 4 + h];
  int c = lane * 4;
  float4 bb = *(const float4*)&b1[c];
  ushort4 o;
  o.x = f2bf(fmaxf(ax * si + bb.x, 0.f));
  o.y = f2bf(fmaxf(ay * si + bb.y, 0.f));
  o.z = f2bf(fmaxf(az * si + bb.z, 0.f));
  o.w = f2bf(fmaxf(aw * si + bb.w, 0.f));
  *(ushort4*)&X2b[(size_t)n * C1 + c] = o;
}

// layer2: wave per node; lane covers 2 channels (128 total); 256B row read/edge.
__global__ __launch_bounds__(256) void agg2(const int* __restrict__ rowptr,
                                            const int* __restrict__ colsrc,
                                            const ushort_t* __restrict__ Hb,
                                            const float* __restrict__ P,
                                            const float* __restrict__ sinv,
                                            const float* __restrict__ b2,
                                            float* __restrict__ out) {
  int wave = threadIdx.x >> 6, lane = threadIdx.x & 63;
  int n = blockIdx.x * 4 + wave;
  if (n >= N_NODES) return;
  int beg = rowptr[n], end = rowptr[n + 1];
  float ax0 = 0.f, ax1 = 0.f, ax2 = 0.f, ax3 = 0.f;
  float ay0 = 0.f, ay1 = 0.f, ay2 = 0.f, ay3 = 0.f;
  int i = beg;
  for (; i + 4 <= end; i += 4) {
    int s0 = colsrc[i], s1 = colsrc[i + 1], s2 = colsrc[i + 2], s3 = colsrc[i + 3];
    float w0 = P[i], w1 = P[i + 1], w2 = P[i + 2], w3 = P[i + 3];
    ushort2 v0 = *(const ushort2*)&Hb[(size_t)s0 * F_OUT + lane * 2];
    ushort2 v1 = *(const ushort2*)&Hb[(size_t)s1 * F_OUT + lane * 2];
    ushort2 v2 = *(const ushort2*)&Hb[(size_t)s2 * F_OUT + lane * 2];
    ushort2 v3 = *(const ushort2*)&Hb[(size_t)s3 * F_OUT + lane * 2];
    ax0 = fmaf(w0, b2f(v0.x), ax0); ay0 = fmaf(w0, b2f(v0.y), ay0);
    ax1 = fmaf(w1, b2f(v1.x), ax1); ay1 = fmaf(w1, b2f(v1.y), ay1);
    ax2 = fmaf(w2, b2f(v2.x), ax2); ay2 = fmaf(w2, b2f(v2.y), ay2);
    ax3 = fmaf(w3, b2f(v3.x), ax3); ay3 = fmaf(w3, b2f(v3.y), ay3);
  }
  for (; i < end; ++i) {
    int s0 = colsrc[i];
    float w0 = P[i];
    ushort2 v0 = *(const ushort2*)&Hb[(size_t)s0 * F_OUT + lane * 2];
    ax0 = fmaf(w0, b2f(v0.x), ax0); ay0 = fmaf(w0, b2f(v0.y), ay0);
  }
  float si = sinv[n];
  int c = lane * 2;
  float2 o;
  o.x = ((ax0 + ax1) + (ax2 + ax3)) * si + b2[c];
  o.y = ((ay0 + ay1) + (ay2 + ay3)) * si + b2[c + 1];
  *(float2*)&out[(size_t)n * F_OUT + c] = o;
}

// ---------------- launch ----------------

extern "C" void kernel_launch(void* const* d_in, const int* in_sizes, int n_in,
                              void* d_out, int out_size, void* d_ws, size_t ws_size,
                              hipStream_t stream) {
  const float* X   = (const float*)d_in[0];
  const int*   EI  = (const int*)d_in[1];
  const float* W1  = (const float*)d_in[2];
  const float* a1s = (const float*)d_in[3];
  const float* a1d = (const float*)d_in[4];
  const float* b1  = (const float*)d_in[5];
  const float* W2  = (const float*)d_in[6];
  const float* a2s = (const float*)d_in[7];
  const float* a2d = (const float*)d_in[8];
  const float* b2  = (const float*)d_in[9];
  float* out = (float*)d_out;

  char* ws = (char*)d_ws;
  size_t off = 0;
  auto alloc = [&](size_t bytes) -> void* {
    void* p = ws + off;
    off += (bytes + 255) & ~(size_t)255;
    return p;
  };
  int* deg        = (int*)alloc((size_t)N_NODES * 4);
  int* fill       = (int*)alloc((size_t)N_NODES * 4);
  int* rowptr     = (int*)alloc((size_t)(N_NODES + 1) * 4);
  int* scantmp    = (int*)alloc((size_t)N_NODES * 4);
  int* bsum       = (int*)alloc((size_t)SCAN_NBLKS * 4);
  int* colsrc     = (int*)alloc((size_t)NET * 4);
  int* coldst     = (int*)alloc((size_t)NET * 4);
  ushort_t* H1b   = (ushort_t*)alloc((size_t)N_NODES * C1 * 2);   // 25.6MB, reused as H2b
  float* ALS1     = (float*)alloc((size_t)N_NODES * HEADS * 4);
  float* ALD1     = (float*)alloc((size_t)N_NODES * HEADS * 4);
  float* SINV1    = (float*)alloc((size_t)N_NODES * HEADS * 4);
  float* P1       = (float*)alloc((size_t)NET * HEADS * 4);       // 13.6MB
  ushort_t* X2b   = (ushort_t*)alloc((size_t)N_NODES * C1 * 2);   // 25.6MB bf16
  float* ALS2     = (float*)alloc((size_t)N_NODES * 4);
  float* ALD2     = (float*)alloc((size_t)N_NODES * 4);
  float* SINV2    = (float*)alloc((size_t)N_NODES * 4);
  float* P2       = (float*)alloc((size_t)NET * 4);               // 3.4MB
  ushort_t* H2b = H1b;  // H1b dead after agg1; gemm2 runs after agg1 in stream order

  hipMemsetAsync(deg, 0, (size_t)N_NODES * 4, stream);
  hipMemsetAsync(fill, 0, (size_t)N_NODES * 4, stream);
  hipMemsetAsync(ALS2, 0, (size_t)N_NODES * 4, stream);   // atomic accumulators
  hipMemsetAsync(ALD2, 0, (size_t)N_NODES * 4, stream);

  count_deg<<<(NET + 255) / 256, 256, 0, stream>>>(EI, deg);
  scan_blocks<<<SCAN_NBLKS, 256, 0, stream>>>(deg, scantmp, bsum);
  scan_bsum<<<1, 256, 0, stream>>>(bsum);
  finalize_rowptr<<<SCAN_NBLKS, 256, 0, stream>>>(scantmp, bsum, rowptr);
  scatter_edges<<<(NET + 255) / 256, 256, 0, stream>>>(EI, rowptr, fill, colsrc, coldst);

  // layer 1
  {
    dim3 grid(C1 / 64, (N_NODES + 63) / 64);
    gemm_bf16<F_IN, C1, 1, float><<<grid, 256, 0, stream>>>(X, W1, H1b, a1s, a1d, ALS1, ALD1);
  }
  scores1<<<(NET + 255) / 256, 256, 0, stream>>>(colsrc, coldst, ALS1, ALD1, P1);
  norm1<<<(N_NODES + 3) / 4, 256, 0, stream>>>(rowptr, P1, SINV1);
  agg1<<<(N_NODES + 3) / 4, 256, 0, stream>>>(rowptr, colsrc, H1b, P1, SINV1, b1, X2b);

  // layer 2
  {
    dim3 grid(F_OUT / 64, (N_NODES + 63) / 64);
    gemm_bf16<C1, F_OUT, 2, ushort_t><<<grid, 256, 0, stream>>>(X2b, W2, H2b, a2s, a2d, ALS2, ALD2);
  }
  scores2<<<(NET + 255) / 256, 256, 0, stream>>>(colsrc, coldst, ALS2, ALD2, P2);
  norm2<<<(N_NODES + 3) / 4, 256, 0, stream>>>(rowptr, P2, SINV2);
  agg2<<<(N_NODES + 3) / 4, 256, 0, stream>>>(rowptr, colsrc, H2b, P2, SINV2, b2, out);
}

// Round 5
// 321.410 us; speedup vs baseline: 1.9882x; 1.1629x over previous
//
#include <hip/hip_runtime.h>
#include <math.h>

#define N_NODES 50000
#define F_IN    128
#define HIDC    64
#define HEADS   4
#define C1      (HEADS*HIDC)   // 256
#define F_OUT   128
#define NE      800000
#define NET     (NE + N_NODES) // 850000 edges incl self-loops
#define NEG_SLOPE 0.2f
#define SCAN_NBLKS ((N_NODES + 255) / 256)   // 196

typedef unsigned short ushort_t;
typedef __attribute__((ext_vector_type(8))) short bf16x8;
typedef __attribute__((ext_vector_type(8))) unsigned short us8;
typedef __attribute__((ext_vector_type(4))) float f32x4;

__device__ __forceinline__ float b2f(ushort_t x) {
  return __uint_as_float(((unsigned int)x) << 16);
}
__device__ __forceinline__ ushort_t f2bf(float f) {  // RNE, no NaN expected
  unsigned int u = __float_as_uint(f);
  return (ushort_t)((u + 0x7fffu + ((u >> 16) & 1u)) >> 16);
}

// ---------------- CSR build ----------------

__global__ void count_deg(const int* __restrict__ ei, int* __restrict__ deg) {
  int e = blockIdx.x * blockDim.x + threadIdx.x;
  if (e >= NET) return;
  int d = (e < NE) ? ei[NE + e] : (e - NE);
  atomicAdd(&deg[d], 1);
}

__global__ __launch_bounds__(256) void scan_blocks(const int* __restrict__ deg,
                                                   int* __restrict__ tmp,
                                                   int* __restrict__ bsum) {
  __shared__ int sh[256];
  int b = blockIdx.x, t = threadIdx.x;
  int idx = b * 256 + t;
  sh[t] = (idx < N_NODES) ? deg[idx] : 0;
  __syncthreads();
#pragma unroll
  for (int off = 1; off < 256; off <<= 1) {
    int u = (t >= off) ? sh[t - off] : 0;
    __syncthreads();
    sh[t] += u;
    __syncthreads();
  }
  if (idx < N_NODES) tmp[idx] = sh[t];
  if (t == 255) bsum[b] = sh[255];
}

__global__ __launch_bounds__(256) void scan_bsum(int* __restrict__ bsum) {
  __shared__ int sh[256];
  int t = threadIdx.x;
  sh[t] = (t < SCAN_NBLKS) ? bsum[t] : 0;
  __syncthreads();
#pragma unroll
  for (int off = 1; off < 256; off <<= 1) {
    int u = (t >= off) ? sh[t - off] : 0;
    __syncthreads();
    sh[t] += u;
    __syncthreads();
  }
  if (t < SCAN_NBLKS) bsum[t] = sh[t];
}

__global__ __launch_bounds__(256) void finalize_rowptr(const int* __restrict__ tmp,
                                                       const int* __restrict__ bsum,
                                                       int* __restrict__ rowptr) {
  int b = blockIdx.x;
  int idx = b * 256 + threadIdx.x;
  if (idx == 0) rowptr[0] = 0;
  if (idx < N_NODES) {
    int off = (b == 0) ? 0 : bsum[b - 1];
    rowptr[idx + 1] = tmp[idx] + off;
  }
}

__global__ void scatter_edges(const int* __restrict__ ei, const int* __restrict__ rowptr,
                              int* __restrict__ fill, int* __restrict__ colsrc,
                              int* __restrict__ coldst) {
  int e = blockIdx.x * blockDim.x + threadIdx.x;
  if (e >= NET) return;
  int s, d;
  if (e < NE) { s = ei[e]; d = ei[NE + e]; }
  else        { s = e - NE; d = s; }
  int pos = atomicAdd(&fill[d], 1);
  int slot = rowptr[d] + pos;
  colsrc[slot] = s;
  coldst[slot] = d;
}

// ---------------- setup: bf16 casts / weight transposes ----------------

__global__ void cast_x(const float* __restrict__ X, ushort_t* __restrict__ Xb) {
  int i = blockIdx.x * blockDim.x + threadIdx.x;   // one float4 per thread
  if (i * 4 >= N_NODES * F_IN) return;
  float4 v = *(const float4*)&X[i * 4];
  ushort4 o;
  o.x = f2bf(v.x); o.y = f2bf(v.y); o.z = f2bf(v.z); o.w = f2bf(v.w);
  *(ushort4*)&Xb[i * 4] = o;
}

template<int K, int NCOL>
__global__ void transpose_w(const float* __restrict__ W, ushort_t* __restrict__ Wt) {
  int idx = blockIdx.x * blockDim.x + threadIdx.x;
  if (idx >= K * NCOL) return;
  int k = idx / NCOL, n = idx - k * NCOL;
  Wt[(size_t)n * K + k] = f2bf(W[idx]);
}

// ---------------- MFMA bf16 GEMM: C[M,NCOL] = A[M,K] @ Bt[NCOL,K]^T ----------------
// 128x128 block tile, 4 waves (2x2), 64x64 per wave = 4x4 fragments of 16x16x32.
// A,Bt row-major bf16. C bf16 via LDS-bounce epilogue.

#define BKS 64
#define LDT 72     // padded K-stride (144B rows: 16B aligned, bank-shift 4)

template<int K, int NCOL>
__global__ __launch_bounds__(256) void gemm_mfma(const ushort_t* __restrict__ A,
                                                 const ushort_t* __restrict__ Bt,
                                                 ushort_t* __restrict__ C) {
  __shared__ __align__(16) char smem[2 * 128 * LDT * 2];   // 36,864B
  ushort_t (*Asl)[LDT] = (ushort_t(*)[LDT])smem;
  ushort_t (*Bsl)[LDT] = (ushort_t(*)[LDT])(smem + 128 * LDT * 2);
  ushort_t (*Ep)[136]  = (ushort_t(*)[136])smem;           // epilogue alias (34,816B)

  const int tid = threadIdx.x;
  const int lane = tid & 63;
  const int wave = tid >> 6;
  const int wr = wave >> 1, wc = wave & 1;
  const int row0 = blockIdx.y * 128;
  const int col0 = blockIdx.x * 128;
  const int l15 = lane & 15, l4 = lane >> 4;

  f32x4 acc[4][4] = {};

  for (int k0 = 0; k0 < K; k0 += BKS) {
    // stage A: 128 rows x 64 k (1024 8-elem segments, 4 per thread)
#pragma unroll
    for (int i = 0; i < 4; ++i) {
      int seg = tid + i * 256;
      int row = seg >> 3, kq = (seg & 7) * 8;
      int arow = row0 + row;
      us8 v = {0, 0, 0, 0, 0, 0, 0, 0};
      if (arow < N_NODES) v = *(const us8*)&A[(size_t)arow * K + k0 + kq];
      *(us8*)&Asl[row][kq] = v;
    }
    // stage B: 128 cols x 64 k
#pragma unroll
    for (int i = 0; i < 4; ++i) {
      int seg = tid + i * 256;
      int row = seg >> 3, kq = (seg & 7) * 8;
      us8 v = *(const us8*)&Bt[(size_t)(col0 + row) * K + k0 + kq];
      *(us8*)&Bsl[row][kq] = v;
    }
    __syncthreads();
#pragma unroll
    for (int kk = 0; kk < BKS; kk += 32) {
      bf16x8 af[4], bf[4];
#pragma unroll
      for (int mi = 0; mi < 4; ++mi)
        af[mi] = *(const bf16x8*)&Asl[wr * 64 + mi * 16 + l15][kk + l4 * 8];
#pragma unroll
      for (int ni = 0; ni < 4; ++ni)
        bf[ni] = *(const bf16x8*)&Bsl[wc * 64 + ni * 16 + l15][kk + l4 * 8];
#pragma unroll
      for (int mi = 0; mi < 4; ++mi)
#pragma unroll
        for (int ni = 0; ni < 4; ++ni)
          acc[mi][ni] = __builtin_amdgcn_mfma_f32_16x16x32_bf16(af[mi], bf[ni], acc[mi][ni], 0, 0, 0);
    }
    __syncthreads();
  }

  // epilogue: acc -> LDS (bf16) -> coalesced global
#pragma unroll
  for (int mi = 0; mi < 4; ++mi)
#pragma unroll
    for (int ni = 0; ni < 4; ++ni)
#pragma unroll
      for (int r = 0; r < 4; ++r)
        Ep[wr * 64 + mi * 16 + l4 * 4 + r][wc * 64 + ni * 16 + l15] = f2bf(acc[mi][ni][r]);
  __syncthreads();
  {
    int row = tid >> 1, half = tid & 1;
    int grow = row0 + row;
    if (grow < N_NODES) {
#pragma unroll
      for (int i = 0; i < 8; ++i)
        *(us8*)&C[(size_t)grow * NCOL + col0 + half * 64 + i * 8] =
            *(const us8*)&Ep[row][half * 64 + i * 8];
    }
  }
}

// ---------------- attention logits (bf16 H) ----------------

__global__ __launch_bounds__(256) void al_heads_b(const ushort_t* __restrict__ Hb,
                                                  const float* __restrict__ a_s,
                                                  const float* __restrict__ a_d,
                                                  float* __restrict__ als,
                                                  float* __restrict__ ald) {
  int n = blockIdx.x;
  int tid = threadIdx.x;
  int h = tid >> 6, lane = tid & 63;
  float v = b2f(Hb[(size_t)n * C1 + tid]);
  float ps = v * a_s[tid], pd = v * a_d[tid];
#pragma unroll
  for (int off = 32; off; off >>= 1) {
    ps += __shfl_down(ps, off, 64);
    pd += __shfl_down(pd, off, 64);
  }
  if (lane == 0) { als[n * HEADS + h] = ps; ald[n * HEADS + h] = pd; }
}

__global__ __launch_bounds__(256) void al_single_b(const ushort_t* __restrict__ Hb,
                                                   const float* __restrict__ a_s,
                                                   const float* __restrict__ a_d,
                                                   float* __restrict__ als,
                                                   float* __restrict__ ald) {
  int wave = threadIdx.x >> 6, lane = threadIdx.x & 63;
  int n = blockIdx.x * 4 + wave;
  if (n >= N_NODES) return;
  float v0 = b2f(Hb[(size_t)n * F_OUT + lane]);
  float v1 = b2f(Hb[(size_t)n * F_OUT + 64 + lane]);
  float ps = v0 * a_s[lane] + v1 * a_s[64 + lane];
  float pd = v0 * a_d[lane] + v1 * a_d[64 + lane];
#pragma unroll
  for (int off = 32; off; off >>= 1) {
    ps += __shfl_down(ps, off, 64);
    pd += __shfl_down(pd, off, 64);
  }
  if (lane == 0) { als[n] = ps; ald[n] = pd; }
}

// ---------------- edge-parallel softmax numerators ----------------

__global__ void scores1(const int* __restrict__ colsrc, const int* __restrict__ coldst,
                        const float* __restrict__ als, const float* __restrict__ ald,
                        float* __restrict__ P) {
  int i = blockIdx.x * blockDim.x + threadIdx.x;
  if (i >= NET) return;
  int s = colsrc[i], d = coldst[i];
  float4 as = *(const float4*)&als[s * 4];
  float4 ad = *(const float4*)&ald[d * 4];
  float4 p;
  float sc;
  sc = as.x + ad.x; sc = sc > 0.f ? sc : NEG_SLOPE * sc; p.x = __expf(sc);
  sc = as.y + ad.y; sc = sc > 0.f ? sc : NEG_SLOPE * sc; p.y = __expf(sc);
  sc = as.z + ad.z; sc = sc > 0.f ? sc : NEG_SLOPE * sc; p.z = __expf(sc);
  sc = as.w + ad.w; sc = sc > 0.f ? sc : NEG_SLOPE * sc; p.w = __expf(sc);
  *(float4*)&P[(size_t)i * 4] = p;
}

__global__ void scores2(const int* __restrict__ colsrc, const int* __restrict__ coldst,
                        const float* __restrict__ als, const float* __restrict__ ald,
                        float* __restrict__ P) {
  int i = blockIdx.x * blockDim.x + threadIdx.x;
  if (i >= NET) return;
  float sc = als[colsrc[i]] + ald[coldst[i]];
  sc = sc > 0.f ? sc : NEG_SLOPE * sc;
  P[i] = __expf(sc);
}

// ---------------- per-node denominators (inverse) ----------------

__global__ __launch_bounds__(256) void norm1(const int* __restrict__ rowptr,
                                             const float* __restrict__ P,
                                             float* __restrict__ sinv) {
  int wave = threadIdx.x >> 6, lane = threadIdx.x & 63;
  int n = blockIdx.x * 4 + wave;
  if (n >= N_NODES) return;
  int beg = rowptr[n], end = rowptr[n + 1];
  float s0 = 0.f, s1 = 0.f, s2 = 0.f, s3 = 0.f;
  for (int i = beg + lane; i < end; i += 64) {
    float4 p = *(const float4*)&P[(size_t)i * 4];
    s0 += p.x; s1 += p.y; s2 += p.z; s3 += p.w;
  }
#pragma unroll
  for (int off = 32; off; off >>= 1) {
    s0 += __shfl_down(s0, off, 64);
    s1 += __shfl_down(s1, off, 64);
    s2 += __shfl_down(s2, off, 64);
    s3 += __shfl_down(s3, off, 64);
  }
  if (lane == 0) {
    float4 r = make_float4(1.f / s0, 1.f / s1, 1.f / s2, 1.f / s3);
    *(float4*)&sinv[n * 4] = r;
  }
}

__global__ __launch_bounds__(256) void norm2(const int* __restrict__ rowptr,
                                             const float* __restrict__ P,
                                             float* __restrict__ sinv) {
  int wave = threadIdx.x >> 6, lane = threadIdx.x & 63;
  int n = blockIdx.x * 4 + wave;
  if (n >= N_NODES) return;
  int beg = rowptr[n], end = rowptr[n + 1];
  float s = 0.f;
  for (int i = beg + lane; i < end; i += 64) s += P[i];
#pragma unroll
  for (int off = 32; off; off >>= 1) s += __shfl_down(s, off, 64);
  if (lane == 0) sinv[n] = 1.f / s;
}

// ---------------- weighted gather aggregation (bf16 messages) ----------------

__global__ __launch_bounds__(256) void agg1(const int* __restrict__ rowptr,
                                            const int* __restrict__ colsrc,
                                            const ushort_t* __restrict__ Hb,
                                            const float* __restrict__ P,
                                            const float* __restrict__ sinv,
                                            const float* __restrict__ b1,
                                            ushort_t* __restrict__ X2b) {
  int wave = threadIdx.x >> 6, lane = threadIdx.x & 63;
  int n = blockIdx.x * 4 + wave;
  if (n >= N_NODES) return;
  int h = lane >> 4;
  int beg = rowptr[n], end = rowptr[n + 1];
  float4 a0 = {0, 0, 0, 0}, a1 = a0, a2 = a0, a3 = a0;
  int i = beg;
  for (; i + 4 <= end; i += 4) {
    int s0 = colsrc[i], s1 = colsrc[i + 1], s2 = colsrc[i + 2], s3 = colsrc[i + 3];
    float w0 = P[(size_t)i * 4 + h];
    float w1 = P[(size_t)(i + 1) * 4 + h];
    float w2 = P[(size_t)(i + 2) * 4 + h];
    float w3 = P[(size_t)(i + 3) * 4 + h];
    ushort4 v0 = *(const ushort4*)&Hb[(size_t)s0 * C1 + lane * 4];
    ushort4 v1 = *(const ushort4*)&Hb[(size_t)s1 * C1 + lane * 4];
    ushort4 v2 = *(const ushort4*)&Hb[(size_t)s2 * C1 + lane * 4];
    ushort4 v3 = *(const ushort4*)&Hb[(size_t)s3 * C1 + lane * 4];
    a0.x = fmaf(w0, b2f(v0.x), a0.x); a0.y = fmaf(w0, b2f(v0.y), a0.y);
    a0.z = fmaf(w0, b2f(v0.z), a0.z); a0.w = fmaf(w0, b2f(v0.w), a0.w);
    a1.x = fmaf(w1, b2f(v1.x), a1.x); a1.y = fmaf(w1, b2f(v1.y), a1.y);
    a1.z = fmaf(w1, b2f(v1.z), a1.z); a1.w = fmaf(w1, b2f(v1.w), a1.w);
    a2.x = fmaf(w2, b2f(v2.x), a2.x); a2.y = fmaf(w2, b2f(v2.y), a2.y);
    a2.z = fmaf(w2, b2f(v2.z), a2.z); a2.w = fmaf(w2, b2f(v2.w), a2.w);
    a3.x = fmaf(w3, b2f(v3.x), a3.x); a3.y = fmaf(w3, b2f(v3.y), a3.y);
    a3.z = fmaf(w3, b2f(v3.z), a3.z); a3.w = fmaf(w3, b2f(v3.w), a3.w);
  }
  for (; i < end; ++i) {
    int s0 = colsrc[i];
    float w0 = P[(size_t)i * 4 + h];
    ushort4 v0 = *(const ushort4*)&Hb[(size_t)s0 * C1 + lane * 4];
    a0.x = fmaf(w0, b2f(v0.x), a0.x); a0.y = fmaf(w0, b2f(v0.y), a0.y);
    a0.z = fmaf(w0, b2f(v0.z), a0.z); a0.w = fmaf(w0, b2f(v0.w), a0.w);
  }
  float ax = (a0.x + a1.x) + (a2.x + a3.x);
  float ay = (a0.y + a1.y) + (a2.y + a3.y);
  float az = (a0.z + a1.z) + (a2.z + a3.z);
  float aw = (a0.w + a1.w) + (a2.w + a3.w);
  float si = sinv[n * 4 + h];
  int c = lane * 4;
  float4 bb = *(const float4*)&b1[c];
  ushort4 o;
  o.x = f2bf(fmaxf(ax * si + bb.x, 0.f));
  o.y = f2bf(fmaxf(ay * si + bb.y, 0.f));
  o.z = f2bf(fmaxf(az * si + bb.z, 0.f));
  o.w = f2bf(fmaxf(aw * si + bb.w, 0.f));
  *(ushort4*)&X2b[(size_t)n * C1 + c] = o;
}

__global__ __launch_bounds__(256) void agg2(const int* __restrict__ rowptr,
                                            const int* __restrict__ colsrc,
                                            const ushort_t* __restrict__ Hb,
                                            const float* __restrict__ P,
                                            const float* __restrict__ sinv,
                                            const float* __restrict__ b2,
                                            float* __restrict__ out) {
  int wave = threadIdx.x >> 6, lane = threadIdx.x & 63;
  int n = blockIdx.x * 4 + wave;
  if (n >= N_NODES) return;
  int beg = rowptr[n], end = rowptr[n + 1];
  float ax0 = 0.f, ax1 = 0.f, ax2 = 0.f, ax3 = 0.f;
  float ay0 = 0.f, ay1 = 0.f, ay2 = 0.f, ay3 = 0.f;
  int i = beg;
  for (; i + 4 <= end; i += 4) {
    int s0 = colsrc[i], s1 = colsrc[i + 1], s2 = colsrc[i + 2], s3 = colsrc[i + 3];
    float w0 = P[i], w1 = P[i + 1], w2 = P[i + 2], w3 = P[i + 3];
    ushort2 v0 = *(const ushort2*)&Hb[(size_t)s0 * F_OUT + lane * 2];
    ushort2 v1 = *(const ushort2*)&Hb[(size_t)s1 * F_OUT + lane * 2];
    ushort2 v2 = *(const ushort2*)&Hb[(size_t)s2 * F_OUT + lane * 2];
    ushort2 v3 = *(const ushort2*)&Hb[(size_t)s3 * F_OUT + lane * 2];
    ax0 = fmaf(w0, b2f(v0.x), ax0); ay0 = fmaf(w0, b2f(v0.y), ay0);
    ax1 = fmaf(w1, b2f(v1.x), ax1); ay1 = fmaf(w1, b2f(v1.y), ay1);
    ax2 = fmaf(w2, b2f(v2.x), ax2); ay2 = fmaf(w2, b2f(v2.y), ay2);
    ax3 = fmaf(w3, b2f(v3.x), ax3); ay3 = fmaf(w3, b2f(v3.y), ay3);
  }
  for (; i < end; ++i) {
    int s0 = colsrc[i];
    float w0 = P[i];
    ushort2 v0 = *(const ushort2*)&Hb[(size_t)s0 * F_OUT + lane * 2];
    ax0 = fmaf(w0, b2f(v0.x), ax0); ay0 = fmaf(w0, b2f(v0.y), ay0);
  }
  float si = sinv[n];
  int c = lane * 2;
  float2 o;
  o.x = ((ax0 + ax1) + (ax2 + ax3)) * si + b2[c];
  o.y = ((ay0 + ay1) + (ay2 + ay3)) * si + b2[c + 1];
  *(float2*)&out[(size_t)n * F_OUT + c] = o;
}

// ---------------- launch ----------------

extern "C" void kernel_launch(void* const* d_in, const int* in_sizes, int n_in,
                              void* d_out, int out_size, void* d_ws, size_t ws_size,
                              hipStream_t stream) {
  const float* X   = (const float*)d_in[0];
  const int*   EI  = (const int*)d_in[1];
  const float* W1  = (const float*)d_in[2];
  const float* a1s = (const float*)d_in[3];
  const float* a1d = (const float*)d_in[4];
  const float* b1  = (const float*)d_in[5];
  const float* W2  = (const float*)d_in[6];
  const float* a2s = (const float*)d_in[7];
  const float* a2d = (const float*)d_in[8];
  const float* b2  = (const float*)d_in[9];
  float* out = (float*)d_out;

  char* ws = (char*)d_ws;
  size_t off = 0;
  auto alloc = [&](size_t bytes) -> void* {
    void* p = ws + off;
    off += (bytes + 255) & ~(size_t)255;
    return p;
  };
  int* deg        = (int*)alloc((size_t)N_NODES * 4);
  int* fill       = (int*)alloc((size_t)N_NODES * 4);
  int* rowptr     = (int*)alloc((size_t)(N_NODES + 1) * 4);
  int* scantmp    = (int*)alloc((size_t)N_NODES * 4);
  int* bsum       = (int*)alloc((size_t)SCAN_NBLKS * 4);
  int* colsrc     = (int*)alloc((size_t)NET * 4);
  int* coldst     = (int*)alloc((size_t)NET * 4);
  ushort_t* Xb    = (ushort_t*)alloc((size_t)N_NODES * F_IN * 2);  // 12.8MB
  ushort_t* W1t   = (ushort_t*)alloc((size_t)C1 * F_IN * 2);       // [256][128]
  ushort_t* W2t   = (ushort_t*)alloc((size_t)F_OUT * C1 * 2);      // [128][256]
  ushort_t* H1b   = (ushort_t*)alloc((size_t)N_NODES * C1 * 2);    // 25.6MB, reused as H2b
  float* ALS1     = (float*)alloc((size_t)N_NODES * HEADS * 4);
  float* ALD1     = (float*)alloc((size_t)N_NODES * HEADS * 4);
  float* SINV1    = (float*)alloc((size_t)N_NODES * HEADS * 4);
  float* P1       = (float*)alloc((size_t)NET * HEADS * 4);        // 13.6MB
  ushort_t* X2b   = (ushort_t*)alloc((size_t)N_NODES * C1 * 2);    // 25.6MB
  float* ALS2     = (float*)alloc((size_t)N_NODES * 4);
  float* ALD2     = (float*)alloc((size_t)N_NODES * 4);
  float* SINV2    = (float*)alloc((size_t)N_NODES * 4);
  float* P2       = (float*)alloc((size_t)NET * 4);
  ushort_t* H2b = H1b;  // H1b dead after agg1

  hipMemsetAsync(deg, 0, (size_t)N_NODES * 4, stream);
  hipMemsetAsync(fill, 0, (size_t)N_NODES * 4, stream);

  // CSR build
  count_deg<<<(NET + 255) / 256, 256, 0, stream>>>(EI, deg);
  scan_blocks<<<SCAN_NBLKS, 256, 0, stream>>>(deg, scantmp, bsum);
  scan_bsum<<<1, 256, 0, stream>>>(bsum);
  finalize_rowptr<<<SCAN_NBLKS, 256, 0, stream>>>(scantmp, bsum, rowptr);
  scatter_edges<<<(NET + 255) / 256, 256, 0, stream>>>(EI, rowptr, fill, colsrc, coldst);

  // setup casts/transposes
  cast_x<<<(N_NODES * F_IN / 4 + 255) / 256, 256, 0, stream>>>(X, Xb);
  transpose_w<F_IN, C1><<<(F_IN * C1 + 255) / 256, 256, 0, stream>>>(W1, W1t);
  transpose_w<C1, F_OUT><<<(C1 * F_OUT + 255) / 256, 256, 0, stream>>>(W2, W2t);

  // layer 1
  {
    dim3 grid(C1 / 128, (N_NODES + 127) / 128);
    gemm_mfma<F_IN, C1><<<grid, 256, 0, stream>>>(Xb, W1t, H1b);
  }
  al_heads_b<<<N_NODES, 256, 0, stream>>>(H1b, a1s, a1d, ALS1, ALD1);
  scores1<<<(NET + 255) / 256, 256, 0, stream>>>(colsrc, coldst, ALS1, ALD1, P1);
  norm1<<<(N_NODES + 3) / 4, 256, 0, stream>>>(rowptr, P1, SINV1);
  agg1<<<(N_NODES + 3) / 4, 256, 0, stream>>>(rowptr, colsrc, H1b, P1, SINV1, b1, X2b);

  // layer 2
  {
    dim3 grid(F_OUT / 128, (N_NODES + 127) / 128);
    gemm_mfma<C1, F_OUT><<<grid, 256, 0, stream>>>(X2b, W2t, H2b);
  }
  al_single_b<<<(N_NODES + 3) / 4, 256, 0, stream>>>(H2b, a2s, a2d, ALS2, ALD2);
  scores2<<<(NET + 255) / 256, 256, 0, stream>>>(colsrc, coldst, ALS2, ALD2, P2);
  norm2<<<(N_NODES + 3) / 4, 256, 0, stream>>>(rowptr, P2, SINV2);
  agg2<<<(N_NODES + 3) / 4, 256, 0, stream>>>(rowptr, colsrc, H2b, P2, SINV2, b2, out);
}